// Round 6
// baseline (1300.709 us; speedup 1.0000x reference)
//
#include <hip/hip_runtime.h>
#include <hip/hip_bf16.h>
#include <math.h>

#define NNODES 100000
#define NBMAX 512          // bucket arrays sized to 512; actual nb = ceil(N/256) = 391
#define CH 8192            // edges per partition block
#define AGG_BLOCKS 2048    // persistent agg128 grid: 2048 blocks x 4 waves = 8192 waves

typedef __hip_bfloat16 bf16;
typedef __attribute__((ext_vector_type(8))) short short8;   // bf16x8 MFMA A/B frag
typedef __attribute__((ext_vector_type(4))) float f32x4;    // MFMA C/D frag

__device__ inline unsigned pack_bf16x2(float a, float b) {
    __hip_bfloat162 p;
    p.x = __float2bfloat16(a);
    p.y = __float2bfloat16(b);
    return *(unsigned*)&p;
}

__device__ inline float2 unpack_bf16x2(unsigned u) {
    __hip_bfloat162 p = *(__hip_bfloat162*)&u;
    return make_float2(__bfloat162float(p.x), __bfloat162float(p.y));
}

// ---------------- phase A: bucket histogram (bucket = dst >> 8) ----------------
__global__ __launch_bounds__(256) void bucket_hist(const int* __restrict__ dst,
                                                   int* __restrict__ bcount, int E, int nb) {
    __shared__ int hist[NBMAX];
    int t = threadIdx.x;
    for (int i = t; i < NBMAX; i += 256) hist[i] = 0;
    __syncthreads();
    int e0 = blockIdx.x * CH;
#pragma unroll
    for (int k = 0; k < 32; ++k) {
        int e = e0 + t + k * 256;
        if (e < E) atomicAdd(&hist[dst[e] >> 8], 1);
    }
    __syncthreads();
    for (int i = t; i < nb; i += 256)
        if (hist[i]) atomicAdd(&bcount[i], hist[i]);
}

// ---------------- phase B: scan bucket counts (1 block, 512 threads) ----------------
__global__ __launch_bounds__(512) void bucket_scan(const int* __restrict__ bcount,
                                                   int* __restrict__ boff,
                                                   int* __restrict__ bcursor,
                                                   int* __restrict__ off, int nb, int n) {
    __shared__ int wsum[8];
    int t = threadIdx.x;
    int v = (t < nb) ? bcount[t] : 0;
    int lane = t & 63, wv = t >> 6;
    int incl = v;
#pragma unroll
    for (int d = 1; d < 64; d <<= 1) {
        int x = __shfl_up(incl, d, 64);
        if (lane >= d) incl += x;
    }
    if (lane == 63) wsum[wv] = incl;
    __syncthreads();
    int wo = 0;
    for (int k = 0; k < wv; ++k) wo += wsum[k];
    int excl = wo + incl - v;
    if (t <= nb) {
        boff[t] = excl;
        if (t < nb) bcursor[t] = excl;
    }
    if (t == nb) off[n] = excl;      // grand total == E
}

// ---------------- phase C: partition edges into bucket-contiguous ranges ----------------
__global__ __launch_bounds__(256) void partition(const int* __restrict__ src,
                                                 const int* __restrict__ dst,
                                                 int* __restrict__ bcursor,
                                                 int2* __restrict__ part, int E, int nb) {
    __shared__ int hist[NBMAX];
    __shared__ int lstart[NBMAX];
    __shared__ int gbase[NBMAX];
    __shared__ int cursor[NBMAX];
    __shared__ int2 sorted[CH];
    int t = threadIdx.x;
    int e0 = blockIdx.x * CH;
    for (int i = t; i < NBMAX; i += 256) hist[i] = 0;
    __syncthreads();
    int mys[32], myd[32];
#pragma unroll
    for (int k = 0; k < 32; ++k) {
        int e = e0 + t + k * 256;
        int s = 0, d = -1;
        if (e < E) { s = src[e]; d = dst[e]; }
        mys[k] = s; myd[k] = d;
        if (d >= 0) atomicAdd(&hist[d >> 8], 1);
    }
    __syncthreads();
    if (t < 64) {
        int base = t * 8;
        int tmp[8];
        int sum = 0;
#pragma unroll
        for (int j = 0; j < 8; ++j) { tmp[j] = hist[base + j]; sum += tmp[j]; }
        int incl = sum;
#pragma unroll
        for (int d = 1; d < 64; d <<= 1) {
            int x = __shfl_up(incl, d, 64);
            if (t >= d) incl += x;
        }
        int excl = incl - sum;
#pragma unroll
        for (int j = 0; j < 8; ++j) {
            lstart[base + j] = excl;
            cursor[base + j] = excl;
            excl += tmp[j];
        }
    }
    __syncthreads();
    for (int i = t; i < nb; i += 256) {
        int c = hist[i];
        gbase[i] = c ? atomicAdd(&bcursor[i], c) : 0;
    }
    __syncthreads();
#pragma unroll
    for (int k = 0; k < 32; ++k) {
        int d = myd[k];
        if (d >= 0) {
            int lpos = atomicAdd(&cursor[d >> 8], 1);
            sorted[lpos] = make_int2(mys[k], d);
        }
    }
    __syncthreads();
    int cnt = min(CH, E - e0);
    for (int i = t; i < cnt; i += 256) {
        int2 rec = sorted[i];
        int b = rec.y >> 8;
        part[gbase[b] + (i - lstart[b])] = rec;
    }
}

// ---------------- phase D: per-bucket node degrees -> off[], dinv[] ----------------
__global__ __launch_bounds__(256) void bucket_nodes(const int2* __restrict__ part,
                                                    const int* __restrict__ boff,
                                                    float* __restrict__ dinv,
                                                    int* __restrict__ off, int n) {
    __shared__ int ndeg[256];
    __shared__ int ws2[4];
    int b = blockIdx.x;
    int t = threadIdx.x;
    ndeg[t] = 0;
    __syncthreads();
    int r0 = boff[b], r1 = boff[b + 1];
    for (int i = r0 + t; i < r1; i += 256)
        atomicAdd(&ndeg[part[i].y & 255], 1);
    __syncthreads();
    int deg = ndeg[t];
    int node = b * 256 + t;
    int lane = t & 63, wv = t >> 6;
    int incl = deg;
#pragma unroll
    for (int d = 1; d < 64; d <<= 1) {
        int x = __shfl_up(incl, d, 64);
        if (lane >= d) incl += x;
    }
    if (lane == 63) ws2[wv] = incl;
    __syncthreads();
    int wo = 0;
    for (int k = 0; k < wv; ++k) wo += ws2[k];
    if (node < n) {
        off[node] = r0 + wo + incl - deg;
        dinv[node] = rsqrtf((float)(deg + 1));     // +1: self-loop
    }
}

// ---------------- phase E: fine CSR fill (writes stay in bucket's 64KB window) ----------
__global__ __launch_bounds__(256) void fine_fill(const int2* __restrict__ part,
                                                 const int* __restrict__ boff,
                                                 const int* __restrict__ off,
                                                 const float* __restrict__ dinv,
                                                 int2* __restrict__ edges, int n) {
    __shared__ int cur[256];
    __shared__ int offl[256];
    __shared__ float dl[256];
    int b = blockIdx.x;
    int t = threadIdx.x;
    int node = b * 256 + t;
    cur[t] = 0;
    offl[t] = (node < n) ? off[node] : 0;
    dl[t] = (node < n) ? dinv[node] : 0.f;
    __syncthreads();
    int r0 = boff[b], r1 = boff[b + 1];
    for (int i = r0 + t; i < r1; i += 256) {
        int2 rec = part[i];
        int dloc = rec.y & 255;
        int s = rec.x;
        float w = dinv[s] * dl[dloc];
        int lpos = atomicAdd(&cur[dloc], 1);
        edges[offl[dloc] + lpos] = make_int2(s, __float_as_int(w));
    }
}

// ---------------- phase F: sort each row's edges by src (band locality) ----------------
__global__ __launch_bounds__(256) void sort_rows(int2* __restrict__ edges,
                                                 const int* __restrict__ off, int n) {
    int node = blockIdx.x * blockDim.x + threadIdx.x;
    if (node >= n) return;
    int i0 = off[node], i1 = off[node + 1];
    for (int i = i0 + 1; i < i1; ++i) {
        int2 key = edges[i];
        int j = i - 1;
        while (j >= i0 && edges[j].x > key.x) { edges[j + 1] = edges[j]; --j; }
        edges[j + 1] = key;
    }
}

// ---------------- weight prep: WT[n][k] = bf16(W[k][n]) ----------------
__global__ void prep_w(const float* __restrict__ W, bf16* __restrict__ WT, int K, int Nout) {
    int idx = blockIdx.x * blockDim.x + threadIdx.x;
    if (idx >= K * Nout) return;
    int nn = idx / K;
    int kk = idx - nn * K;
    WT[idx] = __float2bfloat16(W[kk * Nout + nn]);
}

// ---------------- MFMA GEMM, A fp32 [n,128] x WT bf16 [128][128] -> bf16 ----------------
__global__ __launch_bounds__(256) void gemm128_f32A(const float* __restrict__ A,
                                                    const bf16* __restrict__ WT,
                                                    bf16* __restrict__ C, int n) {
    int wave = threadIdx.x >> 6;
    int lane = threadIdx.x & 63;
    int m = lane & 15;
    int q = lane >> 4;
    int row_base = blockIdx.x * 64 + wave * 16;
    int arow = min(row_base + m, n - 1);

    f32x4 acc[8];
#pragma unroll
    for (int c = 0; c < 8; ++c) acc[c] = (f32x4)(0.f);

#pragma unroll
    for (int kt = 0; kt < 4; ++kt) {
        const float* ap = &A[(size_t)arow * 128 + kt * 32 + q * 8];
        float4 f0 = *(const float4*)ap;
        float4 f1 = *(const float4*)(ap + 4);
        union { uint4 u; short8 s; } cv;
        cv.u.x = pack_bf16x2(f0.x, f0.y);
        cv.u.y = pack_bf16x2(f0.z, f0.w);
        cv.u.z = pack_bf16x2(f1.x, f1.y);
        cv.u.w = pack_bf16x2(f1.z, f1.w);
        short8 af = cv.s;
#pragma unroll
        for (int c = 0; c < 8; ++c) {
            short8 bf = *(const short8*)&WT[(size_t)(c * 16 + m) * 128 + kt * 32 + q * 8];
            acc[c] = __builtin_amdgcn_mfma_f32_16x16x32_bf16(af, bf, acc[c], 0, 0, 0);
        }
    }
#pragma unroll
    for (int c = 0; c < 8; ++c) {
#pragma unroll
        for (int r = 0; r < 4; ++r) {
            int row = row_base + q * 4 + r;
            if (row < n) C[(size_t)row * 128 + c * 16 + m] = __float2bfloat16(acc[c][r]);
        }
    }
}

// ---------------- MFMA GEMM, A bf16 [n,128] x WT bf16 [128][128] -> bf16 ----------------
__global__ __launch_bounds__(256) void gemm128_bf16A(const bf16* __restrict__ A,
                                                     const bf16* __restrict__ WT,
                                                     bf16* __restrict__ C, int n) {
    int wave = threadIdx.x >> 6;
    int lane = threadIdx.x & 63;
    int m = lane & 15;
    int q = lane >> 4;
    int row_base = blockIdx.x * 64 + wave * 16;
    int arow = min(row_base + m, n - 1);

    f32x4 acc[8];
#pragma unroll
    for (int c = 0; c < 8; ++c) acc[c] = (f32x4)(0.f);

#pragma unroll
    for (int kt = 0; kt < 4; ++kt) {
        short8 af = *(const short8*)&A[(size_t)arow * 128 + kt * 32 + q * 8];
#pragma unroll
        for (int c = 0; c < 8; ++c) {
            short8 bf = *(const short8*)&WT[(size_t)(c * 16 + m) * 128 + kt * 32 + q * 8];
            acc[c] = __builtin_amdgcn_mfma_f32_16x16x32_bf16(af, bf, acc[c], 0, 0, 0);
        }
    }
#pragma unroll
    for (int c = 0; c < 8; ++c) {
#pragma unroll
        for (int r = 0; r < 4; ++r) {
            int row = row_base + q * 4 + r;
            if (row < n) C[(size_t)row * 128 + c * 16 + m] = __float2bfloat16(acc[c][r]);
        }
    }
}

// ---------------- MFMA GEMM, A bf16 [n,128] x WT4 bf16 [32][128] -> bf16 [n,32] ----------------
__global__ __launch_bounds__(256) void gemm32_bf16A(const bf16* __restrict__ A,
                                                    const bf16* __restrict__ WT,
                                                    bf16* __restrict__ C, int n) {
    int wave = threadIdx.x >> 6;
    int lane = threadIdx.x & 63;
    int m = lane & 15;
    int q = lane >> 4;
    int row_base = blockIdx.x * 64 + wave * 16;
    int arow = min(row_base + m, n - 1);

    f32x4 acc[2];
    acc[0] = (f32x4)(0.f);
    acc[1] = (f32x4)(0.f);

#pragma unroll
    for (int kt = 0; kt < 4; ++kt) {
        short8 af = *(const short8*)&A[(size_t)arow * 128 + kt * 32 + q * 8];
#pragma unroll
        for (int c = 0; c < 2; ++c) {
            short8 bf = *(const short8*)&WT[(size_t)(c * 16 + m) * 128 + kt * 32 + q * 8];
            acc[c] = __builtin_amdgcn_mfma_f32_16x16x32_bf16(af, bf, acc[c], 0, 0, 0);
        }
    }
#pragma unroll
    for (int c = 0; c < 2; ++c) {
#pragma unroll
        for (int r = 0; r < 4; ++r) {
            int row = row_base + q * 4 + r;
            if (row < n) C[(size_t)row * 32 + c * 16 + m] = __float2bfloat16(acc[c][r]);
        }
    }
}

// ---------------- aggregation F=128: persistent grid, one wave per node ----------------
// Rows are src-sorted; all 8192 waves sweep src 0->N in near-lockstep => L2-band locality.
__global__ __launch_bounds__(256) void agg128(const bf16* __restrict__ h,
                                              const int* __restrict__ off,
                                              const int2* __restrict__ edges,
                                              const float* __restrict__ dinv,
                                              const float* __restrict__ bias,
                                              bf16* __restrict__ out, int n) {
    int wave0 = blockIdx.x * 4 + (threadIdx.x >> 6);
    int lane = threadIdx.x & 63;
    const unsigned* h32 = (const unsigned*)h;     // row = 64 dwords (128 bf16)
    float2 bv = *(const float2*)&bias[lane * 2];
    for (int wid = wave0; wid < n; wid += AGG_BLOCKS * 4) {
        float dl = dinv[wid];
        float sl = dl * dl;
        float2 f = unpack_bf16x2(h32[(unsigned)wid * 64u + lane]);   // self-loop
        float a0 = f.x * sl, a1 = f.y * sl;
        int i0 = off[wid], i1 = off[wid + 1];
        int i = i0;
        for (; i + 16 <= i1; i += 16) {
            unsigned uu[16];
            float wwv[16];
#pragma unroll
            for (int j = 0; j < 16; ++j) {
                int2 e = edges[i + j];
                int s = __builtin_amdgcn_readfirstlane(e.x);          // wave-uniform
                wwv[j] = __int_as_float(__builtin_amdgcn_readfirstlane(e.y));
                uu[j] = h32[(unsigned)s * 64u + lane];
            }
#pragma unroll
            for (int j = 0; j < 16; ++j) {
                float2 fv = unpack_bf16x2(uu[j]);
                a0 += fv.x * wwv[j]; a1 += fv.y * wwv[j];
            }
        }
        for (; i + 4 <= i1; i += 4) {
            unsigned uu[4];
            float wwv[4];
#pragma unroll
            for (int j = 0; j < 4; ++j) {
                int2 e = edges[i + j];
                int s = __builtin_amdgcn_readfirstlane(e.x);
                wwv[j] = __int_as_float(__builtin_amdgcn_readfirstlane(e.y));
                uu[j] = h32[(unsigned)s * 64u + lane];
            }
#pragma unroll
            for (int j = 0; j < 4; ++j) {
                float2 fv = unpack_bf16x2(uu[j]);
                a0 += fv.x * wwv[j]; a1 += fv.y * wwv[j];
            }
        }
        for (; i < i1; ++i) {
            int2 e = edges[i];
            int s = __builtin_amdgcn_readfirstlane(e.x);
            float w = __int_as_float(__builtin_amdgcn_readfirstlane(e.y));
            float2 fv = unpack_bf16x2(h32[(unsigned)s * 64u + lane]);
            a0 += fv.x * w; a1 += fv.y * w;
        }
        a0 += bv.x; a1 += bv.y;
        a0 = fmaxf(a0, 0.f); a1 = fmaxf(a1, 0.f);     // ReLU (layers 1-3 only)
        ((unsigned*)out)[(unsigned)wid * 64u + lane] = pack_bf16x2(a0, a1);
    }
}

// ---------------- aggregation F=32 bf16 gather + log_softmax -> fp32 ----------------
__global__ __launch_bounds__(256) void agg32_lsm(const bf16* __restrict__ h,
                                                 const int* __restrict__ off,
                                                 const int2* __restrict__ edges,
                                                 const float* __restrict__ dinv,
                                                 const float* __restrict__ bias,
                                                 float* __restrict__ out, int n) {
    int idx = blockIdx.x * blockDim.x + threadIdx.x;
    int node = idx >> 5;
    if (node >= n) return;
    int lane = idx & 31;
    const unsigned short* hu = (const unsigned short*)h;
    float dl = dinv[node];
    float a = __bfloat162float(h[(size_t)node * 32 + lane]) * dl * dl;
    int i0 = off[node], i1 = off[node + 1];
    int i = i0;
    for (; i + 8 <= i1; i += 8) {
        int2 ee[8];
#pragma unroll
        for (int j = 0; j < 8; ++j) ee[j] = edges[i + j];
        unsigned short vv[8];
#pragma unroll
        for (int j = 0; j < 8; ++j) vv[j] = hu[(size_t)ee[j].x * 32 + lane];
#pragma unroll
        for (int j = 0; j < 8; ++j) {
            bf16 b = *(bf16*)&vv[j];
            a += __bfloat162float(b) * __int_as_float(ee[j].y);
        }
    }
    for (; i < i1; ++i) {
        int2 e = edges[i];
        a += __bfloat162float(h[(size_t)e.x * 32 + lane]) * __int_as_float(e.y);
    }
    a += bias[lane];
    float mx = a;
    for (int d = 16; d; d >>= 1) mx = fmaxf(mx, __shfl_xor(mx, d, 32));
    float e = expf(a - mx);
    float ssum = e;
    for (int d = 16; d; d >>= 1) ssum += __shfl_xor(ssum, d, 32);
    out[(size_t)node * 32 + lane] = a - mx - logf(ssum);
}

extern "C" void kernel_launch(void* const* d_in, const int* in_sizes, int n_in,
                              void* d_out, int out_size, void* d_ws, size_t ws_size,
                              hipStream_t stream) {
    const float* x  = (const float*)d_in[0];
    const int*   ei = (const int*)d_in[1];
    const float* W1 = (const float*)d_in[2];
    const float* b1 = (const float*)d_in[3];
    const float* W2 = (const float*)d_in[4];
    const float* b2 = (const float*)d_in[5];
    const float* W3 = (const float*)d_in[6];
    const float* b3 = (const float*)d_in[7];
    const float* W4 = (const float*)d_in[8];
    const float* b4 = (const float*)d_in[9];
    float* out = (float*)d_out;

    const int N = NNODES;
    const int E = in_sizes[1] / 2;
    const int nb = (N + 255) / 256;           // 391 buckets

    char* ws = (char*)d_ws;
    size_t o = 0;
    auto alloc = [&](size_t bytes) -> void* {
        void* p = ws + o;
        o += (bytes + 255) & ~(size_t)255;
        return p;
    };
    int*   bcount  = (int*)alloc((size_t)NBMAX * 4);
    int*   boff    = (int*)alloc((size_t)(NBMAX + 1) * 4);
    int*   bcursor = (int*)alloc((size_t)NBMAX * 4);
    int*   off     = (int*)alloc((size_t)(N + 1) * 4);
    float* dinv    = (float*)alloc((size_t)N * 4);
    int2*  part    = (int2*)alloc((size_t)E * 8);      // aliased as gbuf after build
    int2*  edges   = (int2*)alloc((size_t)E * 8);
    bf16*  wt1     = (bf16*)alloc((size_t)128 * 128 * 2);
    bf16*  wt2     = (bf16*)alloc((size_t)128 * 128 * 2);
    bf16*  wt3     = (bf16*)alloc((size_t)128 * 128 * 2);
    bf16*  wt4     = (bf16*)alloc((size_t)32 * 128 * 2);
    bf16*  hbuf    = (bf16*)alloc((size_t)N * 128 * 2);
    bf16*  gbuf    = (bf16*)part;              // part dead after fine_fill; N*256B == E*8B

    const int* srcv = ei;
    const int* dstv = ei + E;

    hipMemsetAsync(bcount, 0, (size_t)NBMAX * 4, stream);

    int pblocks = (E + CH - 1) / CH;
    bucket_hist<<<pblocks, 256, 0, stream>>>(dstv, bcount, E, nb);
    bucket_scan<<<1, 512, 0, stream>>>(bcount, boff, bcursor, off, nb, N);
    partition<<<pblocks, 256, 0, stream>>>(srcv, dstv, bcursor, part, E, nb);
    bucket_nodes<<<nb, 256, 0, stream>>>(part, boff, dinv, off, N);
    fine_fill<<<nb, 256, 0, stream>>>(part, boff, off, dinv, edges, N);
    sort_rows<<<(N + 255) / 256, 256, 0, stream>>>(edges, off, N);

    prep_w<<<64, 256, 0, stream>>>(W1, wt1, 128, 128);
    prep_w<<<64, 256, 0, stream>>>(W2, wt2, 128, 128);
    prep_w<<<64, 256, 0, stream>>>(W3, wt3, 128, 128);
    prep_w<<<16, 256, 0, stream>>>(W4, wt4, 128, 32);

    int gemm_blocks = (N + 63) / 64;
    int agg32_blocks = (N * 32 + 255) / 256;

    // Layer 1 (A fp32)
    gemm128_f32A<<<gemm_blocks, 256, 0, stream>>>(x, wt1, hbuf, N);
    agg128<<<AGG_BLOCKS, 256, 0, stream>>>(hbuf, off, edges, dinv, b1, gbuf, N);
    // Layer 2
    gemm128_bf16A<<<gemm_blocks, 256, 0, stream>>>(gbuf, wt2, hbuf, N);
    agg128<<<AGG_BLOCKS, 256, 0, stream>>>(hbuf, off, edges, dinv, b2, gbuf, N);
    // Layer 3
    gemm128_bf16A<<<gemm_blocks, 256, 0, stream>>>(gbuf, wt3, hbuf, N);
    agg128<<<AGG_BLOCKS, 256, 0, stream>>>(hbuf, off, edges, dinv, b3, gbuf, N);
    // Layer 4: GEMM to 32 cols, then agg + log_softmax
    gemm32_bf16A<<<gemm_blocks, 256, 0, stream>>>(gbuf, wt4, hbuf, N);
    agg32_lsm<<<agg32_blocks, 256, 0, stream>>>(hbuf, off, edges, dinv, b4, out, N);
}

// Round 7
// 767.311 us; speedup vs baseline: 1.6952x; 1.6952x over previous
//
#include <hip/hip_runtime.h>
#include <hip/hip_bf16.h>
#include <math.h>

#define NNODES 100000
#define NBMAX 512          // bucket arrays sized to 512; actual nb = ceil(N/256) = 391
#define CH 8192            // edges per partition block

typedef __hip_bfloat16 bf16;
typedef __attribute__((ext_vector_type(8))) short short8;   // bf16x8 MFMA A/B frag
typedef __attribute__((ext_vector_type(4))) float f32x4;    // MFMA C/D frag

__device__ inline unsigned pack_bf16x2(float a, float b) {
    __hip_bfloat162 p;
    p.x = __float2bfloat16(a);
    p.y = __float2bfloat16(b);
    return *(unsigned*)&p;
}

__device__ inline float2 unpack_bf16x2(unsigned u) {
    __hip_bfloat162 p = *(__hip_bfloat162*)&u;
    return make_float2(__bfloat162float(p.x), __bfloat162float(p.y));
}

// ---------------- phase A: bucket histogram (bucket = dst >> 8) ----------------
__global__ __launch_bounds__(256) void bucket_hist(const int* __restrict__ dst,
                                                   int* __restrict__ bcount, int E, int nb) {
    __shared__ int hist[NBMAX];
    int t = threadIdx.x;
    for (int i = t; i < NBMAX; i += 256) hist[i] = 0;
    __syncthreads();
    int e0 = blockIdx.x * CH;
#pragma unroll
    for (int k = 0; k < 32; ++k) {
        int e = e0 + t + k * 256;
        if (e < E) atomicAdd(&hist[dst[e] >> 8], 1);
    }
    __syncthreads();
    for (int i = t; i < nb; i += 256)
        if (hist[i]) atomicAdd(&bcount[i], hist[i]);
}

// ---------------- phase B: scan bucket counts (1 block, 512 threads) ----------------
__global__ __launch_bounds__(512) void bucket_scan(const int* __restrict__ bcount,
                                                   int* __restrict__ boff,
                                                   int* __restrict__ bcursor,
                                                   int* __restrict__ off, int nb, int n) {
    __shared__ int wsum[8];
    int t = threadIdx.x;
    int v = (t < nb) ? bcount[t] : 0;
    int lane = t & 63, wv = t >> 6;
    int incl = v;
#pragma unroll
    for (int d = 1; d < 64; d <<= 1) {
        int x = __shfl_up(incl, d, 64);
        if (lane >= d) incl += x;
    }
    if (lane == 63) wsum[wv] = incl;
    __syncthreads();
    int wo = 0;
    for (int k = 0; k < wv; ++k) wo += wsum[k];
    int excl = wo + incl - v;
    if (t <= nb) {
        boff[t] = excl;
        if (t < nb) bcursor[t] = excl;
    }
    if (t == nb) off[n] = excl;      // grand total == E
}

// ---------------- phase C: partition edges into bucket-contiguous ranges ----------------
__global__ __launch_bounds__(256) void partition(const int* __restrict__ src,
                                                 const int* __restrict__ dst,
                                                 int* __restrict__ bcursor,
                                                 int2* __restrict__ part, int E, int nb) {
    __shared__ int hist[NBMAX];
    __shared__ int lstart[NBMAX];
    __shared__ int gbase[NBMAX];
    __shared__ int cursor[NBMAX];
    __shared__ int2 sorted[CH];
    int t = threadIdx.x;
    int e0 = blockIdx.x * CH;
    for (int i = t; i < NBMAX; i += 256) hist[i] = 0;
    __syncthreads();
    int mys[32], myd[32];
#pragma unroll
    for (int k = 0; k < 32; ++k) {
        int e = e0 + t + k * 256;
        int s = 0, d = -1;
        if (e < E) { s = src[e]; d = dst[e]; }
        mys[k] = s; myd[k] = d;
        if (d >= 0) atomicAdd(&hist[d >> 8], 1);
    }
    __syncthreads();
    if (t < 64) {
        int base = t * 8;
        int tmp[8];
        int sum = 0;
#pragma unroll
        for (int j = 0; j < 8; ++j) { tmp[j] = hist[base + j]; sum += tmp[j]; }
        int incl = sum;
#pragma unroll
        for (int d = 1; d < 64; d <<= 1) {
            int x = __shfl_up(incl, d, 64);
            if (t >= d) incl += x;
        }
        int excl = incl - sum;
#pragma unroll
        for (int j = 0; j < 8; ++j) {
            lstart[base + j] = excl;
            cursor[base + j] = excl;
            excl += tmp[j];
        }
    }
    __syncthreads();
    for (int i = t; i < nb; i += 256) {
        int c = hist[i];
        gbase[i] = c ? atomicAdd(&bcursor[i], c) : 0;
    }
    __syncthreads();
#pragma unroll
    for (int k = 0; k < 32; ++k) {
        int d = myd[k];
        if (d >= 0) {
            int lpos = atomicAdd(&cursor[d >> 8], 1);
            sorted[lpos] = make_int2(mys[k], d);
        }
    }
    __syncthreads();
    int cnt = min(CH, E - e0);
    for (int i = t; i < cnt; i += 256) {
        int2 rec = sorted[i];
        int b = rec.y >> 8;
        part[gbase[b] + (i - lstart[b])] = rec;
    }
}

// ---------------- phase D: per-bucket node degrees -> off[], dinv[] ----------------
__global__ __launch_bounds__(256) void bucket_nodes(const int2* __restrict__ part,
                                                    const int* __restrict__ boff,
                                                    float* __restrict__ dinv,
                                                    int* __restrict__ off, int n) {
    __shared__ int ndeg[256];
    __shared__ int ws2[4];
    int b = blockIdx.x;
    int t = threadIdx.x;
    ndeg[t] = 0;
    __syncthreads();
    int r0 = boff[b], r1 = boff[b + 1];
    for (int i = r0 + t; i < r1; i += 256)
        atomicAdd(&ndeg[part[i].y & 255], 1);
    __syncthreads();
    int deg = ndeg[t];
    int node = b * 256 + t;
    int lane = t & 63, wv = t >> 6;
    int incl = deg;
#pragma unroll
    for (int d = 1; d < 64; d <<= 1) {
        int x = __shfl_up(incl, d, 64);
        if (lane >= d) incl += x;
    }
    if (lane == 63) ws2[wv] = incl;
    __syncthreads();
    int wo = 0;
    for (int k = 0; k < wv; ++k) wo += ws2[k];
    if (node < n) {
        off[node] = r0 + wo + incl - deg;
        dinv[node] = rsqrtf((float)(deg + 1));     // +1: self-loop
    }
}

// ---------------- phase E: fine CSR fill (writes stay in bucket's 64KB window) ----------
__global__ __launch_bounds__(256) void fine_fill(const int2* __restrict__ part,
                                                 const int* __restrict__ boff,
                                                 const int* __restrict__ off,
                                                 const float* __restrict__ dinv,
                                                 int2* __restrict__ edges, int n) {
    __shared__ int cur[256];
    __shared__ int offl[256];
    __shared__ float dl[256];
    int b = blockIdx.x;
    int t = threadIdx.x;
    int node = b * 256 + t;
    cur[t] = 0;
    offl[t] = (node < n) ? off[node] : 0;
    dl[t] = (node < n) ? dinv[node] : 0.f;
    __syncthreads();
    int r0 = boff[b], r1 = boff[b + 1];
    for (int i = r0 + t; i < r1; i += 256) {
        int2 rec = part[i];
        int dloc = rec.y & 255;
        int s = rec.x;
        float w = dinv[s] * dl[dloc];
        int lpos = atomicAdd(&cur[dloc], 1);
        edges[offl[dloc] + lpos] = make_int2(s, __float_as_int(w));
    }
}

// ---------------- weight prep: WT[n][k] = bf16(W[k][n]) ----------------
__global__ void prep_w(const float* __restrict__ W, bf16* __restrict__ WT, int K, int Nout) {
    int idx = blockIdx.x * blockDim.x + threadIdx.x;
    if (idx >= K * Nout) return;
    int nn = idx / K;
    int kk = idx - nn * K;
    WT[idx] = __float2bfloat16(W[kk * Nout + nn]);
}

#define WSTRIDE 136   // bf16 elements; 272 B = 17x16 B (aligned), 2-way LDS conflict only

// ---------------- MFMA GEMM (LDS-staged WT), A fp32 [n,128] -> bf16 ----------------
__global__ __launch_bounds__(256) void gemm128_f32A(const float* __restrict__ A,
                                                    const bf16* __restrict__ WT,
                                                    bf16* __restrict__ C, int n) {
    __shared__ bf16 wl[128 * WSTRIDE];   // 34 KB
    int t = threadIdx.x;
#pragma unroll
    for (int l = 0; l < 8; ++l) {
        int chunk = t + l * 256;           // 0..2047, 16B chunks
        int row = chunk >> 4, ch = chunk & 15;
        *(uint4*)&wl[row * WSTRIDE + ch * 8] = *(const uint4*)&WT[row * 128 + ch * 8];
    }
    __syncthreads();
    int wave = t >> 6, lane = t & 63;
    int m = lane & 15, q = lane >> 4;
    int row_base = blockIdx.x * 128 + wave * 32;
    int r0 = min(row_base + m, n - 1);
    int r1 = min(row_base + 16 + m, n - 1);

    f32x4 acc[2][8];
#pragma unroll
    for (int g = 0; g < 2; ++g)
#pragma unroll
        for (int c = 0; c < 8; ++c) acc[g][c] = (f32x4)(0.f);

#pragma unroll
    for (int kt = 0; kt < 4; ++kt) {
        short8 af[2];
#pragma unroll
        for (int g = 0; g < 2; ++g) {
            const float* ap = &A[(size_t)(g ? r1 : r0) * 128 + kt * 32 + q * 8];
            float4 f0 = *(const float4*)ap;
            float4 f1 = *(const float4*)(ap + 4);
            union { uint4 u; short8 s; } cv;
            cv.u.x = pack_bf16x2(f0.x, f0.y);
            cv.u.y = pack_bf16x2(f0.z, f0.w);
            cv.u.z = pack_bf16x2(f1.x, f1.y);
            cv.u.w = pack_bf16x2(f1.z, f1.w);
            af[g] = cv.s;
        }
#pragma unroll
        for (int c = 0; c < 8; ++c) {
            short8 bf = *(const short8*)&wl[(c * 16 + m) * WSTRIDE + kt * 32 + q * 8];
            acc[0][c] = __builtin_amdgcn_mfma_f32_16x16x32_bf16(af[0], bf, acc[0][c], 0, 0, 0);
            acc[1][c] = __builtin_amdgcn_mfma_f32_16x16x32_bf16(af[1], bf, acc[1][c], 0, 0, 0);
        }
    }
#pragma unroll
    for (int g = 0; g < 2; ++g)
#pragma unroll
        for (int c = 0; c < 8; ++c)
#pragma unroll
            for (int r = 0; r < 4; ++r) {
                int row = row_base + g * 16 + q * 4 + r;
                if (row < n) C[(size_t)row * 128 + c * 16 + m] = __float2bfloat16(acc[g][c][r]);
            }
}

// ---------------- MFMA GEMM (LDS-staged WT), A bf16 [n,128] -> bf16 ----------------
__global__ __launch_bounds__(256) void gemm128_bf16A(const bf16* __restrict__ A,
                                                     const bf16* __restrict__ WT,
                                                     bf16* __restrict__ C, int n) {
    __shared__ bf16 wl[128 * WSTRIDE];   // 34 KB
    int t = threadIdx.x;
#pragma unroll
    for (int l = 0; l < 8; ++l) {
        int chunk = t + l * 256;
        int row = chunk >> 4, ch = chunk & 15;
        *(uint4*)&wl[row * WSTRIDE + ch * 8] = *(const uint4*)&WT[row * 128 + ch * 8];
    }
    __syncthreads();
    int wave = t >> 6, lane = t & 63;
    int m = lane & 15, q = lane >> 4;
    int row_base = blockIdx.x * 128 + wave * 32;
    int r0 = min(row_base + m, n - 1);
    int r1 = min(row_base + 16 + m, n - 1);

    f32x4 acc[2][8];
#pragma unroll
    for (int g = 0; g < 2; ++g)
#pragma unroll
        for (int c = 0; c < 8; ++c) acc[g][c] = (f32x4)(0.f);

#pragma unroll
    for (int kt = 0; kt < 4; ++kt) {
        short8 a0 = *(const short8*)&A[(size_t)r0 * 128 + kt * 32 + q * 8];
        short8 a1 = *(const short8*)&A[(size_t)r1 * 128 + kt * 32 + q * 8];
#pragma unroll
        for (int c = 0; c < 8; ++c) {
            short8 bf = *(const short8*)&wl[(c * 16 + m) * WSTRIDE + kt * 32 + q * 8];
            acc[0][c] = __builtin_amdgcn_mfma_f32_16x16x32_bf16(a0, bf, acc[0][c], 0, 0, 0);
            acc[1][c] = __builtin_amdgcn_mfma_f32_16x16x32_bf16(a1, bf, acc[1][c], 0, 0, 0);
        }
    }
#pragma unroll
    for (int g = 0; g < 2; ++g)
#pragma unroll
        for (int c = 0; c < 8; ++c)
#pragma unroll
            for (int r = 0; r < 4; ++r) {
                int row = row_base + g * 16 + q * 4 + r;
                if (row < n) C[(size_t)row * 128 + c * 16 + m] = __float2bfloat16(acc[g][c][r]);
            }
}

// ---------------- MFMA GEMM, A bf16 [n,128] x WT4 bf16 [32][128] -> bf16 [n,32] ----------------
__global__ __launch_bounds__(256) void gemm32_bf16A(const bf16* __restrict__ A,
                                                    const bf16* __restrict__ WT,
                                                    bf16* __restrict__ C, int n) {
    int wave = threadIdx.x >> 6;
    int lane = threadIdx.x & 63;
    int m = lane & 15;
    int q = lane >> 4;
    int row_base = blockIdx.x * 64 + wave * 16;
    int arow = min(row_base + m, n - 1);

    f32x4 acc[2];
    acc[0] = (f32x4)(0.f);
    acc[1] = (f32x4)(0.f);

#pragma unroll
    for (int kt = 0; kt < 4; ++kt) {
        short8 af = *(const short8*)&A[(size_t)arow * 128 + kt * 32 + q * 8];
#pragma unroll
        for (int c = 0; c < 2; ++c) {
            short8 bf = *(const short8*)&WT[(size_t)(c * 16 + m) * 128 + kt * 32 + q * 8];
            acc[c] = __builtin_amdgcn_mfma_f32_16x16x32_bf16(af, bf, acc[c], 0, 0, 0);
        }
    }
#pragma unroll
    for (int c = 0; c < 2; ++c)
#pragma unroll
        for (int r = 0; r < 4; ++r) {
            int row = row_base + q * 4 + r;
            if (row < n) C[(size_t)row * 32 + c * 16 + m] = __float2bfloat16(acc[c][r]);
        }
}

// ---------------- aggregation F=128: one wave/node, 2 edges per gather inst ----------------
// 32 lanes x 8 B cover one 256 B row; halves process edges i and i+1 concurrently.
__global__ __launch_bounds__(256) void agg128(const bf16* __restrict__ h,
                                              const int* __restrict__ off,
                                              const int2* __restrict__ edges,
                                              const float* __restrict__ dinv,
                                              const float* __restrict__ bias,
                                              bf16* __restrict__ out, int n) {
    int wid = (blockIdx.x * blockDim.x + threadIdx.x) >> 6;
    if (wid >= n) return;
    int lane = threadIdx.x & 63;
    int half = lane >> 5;          // which edge of the pair
    int pos = lane & 31;           // 8B chunk within row -> features pos*4..pos*4+3
    const uint2* h2 = (const uint2*)h;   // row = 32 x uint2

    float dl = dinv[wid];
    float sl = (half == 0) ? dl * dl : 0.f;   // self-loop counted once
    uint2 sf = h2[(unsigned)wid * 32u + pos];
    float2 s0 = unpack_bf16x2(sf.x), s1 = unpack_bf16x2(sf.y);
    float a0 = s0.x * sl, a1 = s0.y * sl, a2 = s1.x * sl, a3 = s1.y * sl;

    int i0 = off[wid], i1 = off[wid + 1];
    for (int i = i0; i < i1; i += 16) {
        uint2 gg[8];
        float ww[8];
#pragma unroll
        for (int j = 0; j < 8; ++j) {
            int e = i + j * 2 + half;
            int2 er = edges[min(e, i1 - 1)];
            ww[j] = (e < i1) ? __int_as_float(er.y) : 0.f;
            gg[j] = h2[(unsigned)er.x * 32u + pos];
        }
#pragma unroll
        for (int j = 0; j < 8; ++j) {
            float2 f0 = unpack_bf16x2(gg[j].x);
            float2 f1 = unpack_bf16x2(gg[j].y);
            a0 += f0.x * ww[j]; a1 += f0.y * ww[j];
            a2 += f1.x * ww[j]; a3 += f1.y * ww[j];
        }
    }
    // combine the two halves (lanes l and l^32 hold the same features)
    a0 += __shfl_xor(a0, 32);
    a1 += __shfl_xor(a1, 32);
    a2 += __shfl_xor(a2, 32);
    a3 += __shfl_xor(a3, 32);

    float4 bv = ((const float4*)bias)[pos];
    a0 = fmaxf(a0 + bv.x, 0.f);
    a1 = fmaxf(a1 + bv.y, 0.f);
    a2 = fmaxf(a2 + bv.z, 0.f);
    a3 = fmaxf(a3 + bv.w, 0.f);
    // lane writes dword pos*2+half: features (pos*4+half*2, +1)
    unsigned pk = half ? pack_bf16x2(a2, a3) : pack_bf16x2(a0, a1);
    ((unsigned*)out)[(unsigned)wid * 64u + pos * 2 + half] = pk;
}

// ---------------- aggregation F=32 bf16 gather + log_softmax -> fp32 ----------------
__global__ __launch_bounds__(256) void agg32_lsm(const bf16* __restrict__ h,
                                                 const int* __restrict__ off,
                                                 const int2* __restrict__ edges,
                                                 const float* __restrict__ dinv,
                                                 const float* __restrict__ bias,
                                                 float* __restrict__ out, int n) {
    int idx = blockIdx.x * blockDim.x + threadIdx.x;
    int node = idx >> 5;
    if (node >= n) return;
    int lane = idx & 31;
    const unsigned short* hu = (const unsigned short*)h;
    float dl = dinv[node];
    float a = __bfloat162float(h[(size_t)node * 32 + lane]) * dl * dl;
    int i0 = off[node], i1 = off[node + 1];
    int i = i0;
    for (; i + 8 <= i1; i += 8) {
        int2 ee[8];
#pragma unroll
        for (int j = 0; j < 8; ++j) ee[j] = edges[i + j];
        unsigned short vv[8];
#pragma unroll
        for (int j = 0; j < 8; ++j) vv[j] = hu[(size_t)ee[j].x * 32 + lane];
#pragma unroll
        for (int j = 0; j < 8; ++j) {
            bf16 b = *(bf16*)&vv[j];
            a += __bfloat162float(b) * __int_as_float(ee[j].y);
        }
    }
    for (; i < i1; ++i) {
        int2 e = edges[i];
        a += __bfloat162float(h[(size_t)e.x * 32 + lane]) * __int_as_float(e.y);
    }
    a += bias[lane];
    float mx = a;
    for (int d = 16; d; d >>= 1) mx = fmaxf(mx, __shfl_xor(mx, d, 32));
    float e = expf(a - mx);
    float ssum = e;
    for (int d = 16; d; d >>= 1) ssum += __shfl_xor(ssum, d, 32);
    out[(size_t)node * 32 + lane] = a - mx - logf(ssum);
}

extern "C" void kernel_launch(void* const* d_in, const int* in_sizes, int n_in,
                              void* d_out, int out_size, void* d_ws, size_t ws_size,
                              hipStream_t stream) {
    const float* x  = (const float*)d_in[0];
    const int*   ei = (const int*)d_in[1];
    const float* W1 = (const float*)d_in[2];
    const float* b1 = (const float*)d_in[3];
    const float* W2 = (const float*)d_in[4];
    const float* b2 = (const float*)d_in[5];
    const float* W3 = (const float*)d_in[6];
    const float* b3 = (const float*)d_in[7];
    const float* W4 = (const float*)d_in[8];
    const float* b4 = (const float*)d_in[9];
    float* out = (float*)d_out;

    const int N = NNODES;
    const int E = in_sizes[1] / 2;
    const int nb = (N + 255) / 256;           // 391 buckets

    char* ws = (char*)d_ws;
    size_t o = 0;
    auto alloc = [&](size_t bytes) -> void* {
        void* p = ws + o;
        o += (bytes + 255) & ~(size_t)255;
        return p;
    };
    int*   bcount  = (int*)alloc((size_t)NBMAX * 4);
    int*   boff    = (int*)alloc((size_t)(NBMAX + 1) * 4);
    int*   bcursor = (int*)alloc((size_t)NBMAX * 4);
    int*   off     = (int*)alloc((size_t)(N + 1) * 4);
    float* dinv    = (float*)alloc((size_t)N * 4);
    int2*  part    = (int2*)alloc((size_t)E * 8);      // aliased as gbuf after build
    int2*  edges   = (int2*)alloc((size_t)E * 8);
    bf16*  wt1     = (bf16*)alloc((size_t)128 * 128 * 2);
    bf16*  wt2     = (bf16*)alloc((size_t)128 * 128 * 2);
    bf16*  wt3     = (bf16*)alloc((size_t)128 * 128 * 2);
    bf16*  wt4     = (bf16*)alloc((size_t)32 * 128 * 2);
    bf16*  hbuf    = (bf16*)alloc((size_t)N * 128 * 2);
    bf16*  gbuf    = (bf16*)part;              // part dead after fine_fill; N*256B == E*8B

    const int* srcv = ei;
    const int* dstv = ei + E;

    hipMemsetAsync(bcount, 0, (size_t)NBMAX * 4, stream);

    int pblocks = (E + CH - 1) / CH;
    bucket_hist<<<pblocks, 256, 0, stream>>>(dstv, bcount, E, nb);
    bucket_scan<<<1, 512, 0, stream>>>(bcount, boff, bcursor, off, nb, N);
    partition<<<pblocks, 256, 0, stream>>>(srcv, dstv, bcursor, part, E, nb);
    bucket_nodes<<<nb, 256, 0, stream>>>(part, boff, dinv, off, N);
    fine_fill<<<nb, 256, 0, stream>>>(part, boff, off, dinv, edges, N);

    prep_w<<<64, 256, 0, stream>>>(W1, wt1, 128, 128);
    prep_w<<<64, 256, 0, stream>>>(W2, wt2, 128, 128);
    prep_w<<<64, 256, 0, stream>>>(W3, wt3, 128, 128);
    prep_w<<<16, 256, 0, stream>>>(W4, wt4, 128, 32);

    int gemm128_blocks = (N + 127) / 128;
    int gemm32_blocks = (N + 63) / 64;
    int agg128_blocks = (N + 3) / 4;
    int agg32_blocks = (N * 32 + 255) / 256;

    // Layer 1 (A fp32)
    gemm128_f32A<<<gemm128_blocks, 256, 0, stream>>>(x, wt1, hbuf, N);
    agg128<<<agg128_blocks, 256, 0, stream>>>(hbuf, off, edges, dinv, b1, gbuf, N);
    // Layer 2
    gemm128_bf16A<<<gemm128_blocks, 256, 0, stream>>>(gbuf, wt2, hbuf, N);
    agg128<<<agg128_blocks, 256, 0, stream>>>(hbuf, off, edges, dinv, b2, gbuf, N);
    // Layer 3
    gemm128_bf16A<<<gemm128_blocks, 256, 0, stream>>>(gbuf, wt3, hbuf, N);
    agg128<<<agg128_blocks, 256, 0, stream>>>(hbuf, off, edges, dinv, b3, gbuf, N);
    // Layer 4: GEMM to 32 cols, then agg + log_softmax
    gemm32_bf16A<<<gemm32_blocks, 256, 0, stream>>>(gbuf, wt4, hbuf, N);
    agg32_lsm<<<agg32_blocks, 256, 0, stream>>>(hbuf, off, edges, dinv, b4, out, N);
}

// Round 8
// 641.181 us; speedup vs baseline: 2.0286x; 1.1967x over previous
//
#include <hip/hip_runtime.h>
#include <hip/hip_bf16.h>
#include <math.h>

#define NNODES 100000
#define NBMAX 512          // bucket arrays sized to 512; actual nb = ceil(N/256) = 391
#define CH 8192            // edges per partition block

typedef __hip_bfloat16 bf16;
typedef __attribute__((ext_vector_type(8))) short short8;   // bf16x8 MFMA A/B frag
typedef __attribute__((ext_vector_type(4))) float f32x4;    // MFMA C/D frag
typedef __attribute__((ext_vector_type(2))) float f32x2;

__device__ inline unsigned pack_bf16x2(float a, float b) {
    __hip_bfloat162 p;
    p.x = __float2bfloat16(a);
    p.y = __float2bfloat16(b);
    return *(unsigned*)&p;
}

__device__ inline float2 unpack_bf16x2(unsigned u) {
    __hip_bfloat162 p = *(__hip_bfloat162*)&u;
    return make_float2(__bfloat162float(p.x), __bfloat162float(p.y));
}

__device__ inline unsigned char f32_to_fp8(float v) {
    int p = __builtin_amdgcn_cvt_pk_fp8_f32(v, v, 0, false);   // OCP e4m3 on gfx950
    return (unsigned char)(p & 0xff);
}

// ---------------- phase A: bucket histogram (bucket = dst >> 8) ----------------
__global__ __launch_bounds__(256) void bucket_hist(const int* __restrict__ dst,
                                                   int* __restrict__ bcount, int E, int nb) {
    __shared__ int hist[NBMAX];
    int t = threadIdx.x;
    for (int i = t; i < NBMAX; i += 256) hist[i] = 0;
    __syncthreads();
    int e0 = blockIdx.x * CH;
#pragma unroll
    for (int k = 0; k < 32; ++k) {
        int e = e0 + t + k * 256;
        if (e < E) atomicAdd(&hist[dst[e] >> 8], 1);
    }
    __syncthreads();
    for (int i = t; i < nb; i += 256)
        if (hist[i]) atomicAdd(&bcount[i], hist[i]);
}

// ---------------- phase B: scan bucket counts (1 block, 512 threads) ----------------
__global__ __launch_bounds__(512) void bucket_scan(const int* __restrict__ bcount,
                                                   int* __restrict__ boff,
                                                   int* __restrict__ bcursor,
                                                   int* __restrict__ off, int nb, int n) {
    __shared__ int wsum[8];
    int t = threadIdx.x;
    int v = (t < nb) ? bcount[t] : 0;
    int lane = t & 63, wv = t >> 6;
    int incl = v;
#pragma unroll
    for (int d = 1; d < 64; d <<= 1) {
        int x = __shfl_up(incl, d, 64);
        if (lane >= d) incl += x;
    }
    if (lane == 63) wsum[wv] = incl;
    __syncthreads();
    int wo = 0;
    for (int k = 0; k < wv; ++k) wo += wsum[k];
    int excl = wo + incl - v;
    if (t <= nb) {
        boff[t] = excl;
        if (t < nb) bcursor[t] = excl;
    }
    if (t == nb) off[n] = excl;      // grand total == E
}

// ---------------- phase C: partition edges into bucket-contiguous ranges ----------------
__global__ __launch_bounds__(256) void partition(const int* __restrict__ src,
                                                 const int* __restrict__ dst,
                                                 int* __restrict__ bcursor,
                                                 int2* __restrict__ part, int E, int nb) {
    __shared__ int hist[NBMAX];
    __shared__ int lstart[NBMAX];
    __shared__ int gbase[NBMAX];
    __shared__ int cursor[NBMAX];
    __shared__ int2 sorted[CH];
    int t = threadIdx.x;
    int e0 = blockIdx.x * CH;
    for (int i = t; i < NBMAX; i += 256) hist[i] = 0;
    __syncthreads();
    int mys[32], myd[32];
#pragma unroll
    for (int k = 0; k < 32; ++k) {
        int e = e0 + t + k * 256;
        int s = 0, d = -1;
        if (e < E) { s = src[e]; d = dst[e]; }
        mys[k] = s; myd[k] = d;
        if (d >= 0) atomicAdd(&hist[d >> 8], 1);
    }
    __syncthreads();
    if (t < 64) {
        int base = t * 8;
        int tmp[8];
        int sum = 0;
#pragma unroll
        for (int j = 0; j < 8; ++j) { tmp[j] = hist[base + j]; sum += tmp[j]; }
        int incl = sum;
#pragma unroll
        for (int d = 1; d < 64; d <<= 1) {
            int x = __shfl_up(incl, d, 64);
            if (t >= d) incl += x;
        }
        int excl = incl - sum;
#pragma unroll
        for (int j = 0; j < 8; ++j) {
            lstart[base + j] = excl;
            cursor[base + j] = excl;
            excl += tmp[j];
        }
    }
    __syncthreads();
    for (int i = t; i < nb; i += 256) {
        int c = hist[i];
        gbase[i] = c ? atomicAdd(&bcursor[i], c) : 0;
    }
    __syncthreads();
#pragma unroll
    for (int k = 0; k < 32; ++k) {
        int d = myd[k];
        if (d >= 0) {
            int lpos = atomicAdd(&cursor[d >> 8], 1);
            sorted[lpos] = make_int2(mys[k], d);
        }
    }
    __syncthreads();
    int cnt = min(CH, E - e0);
    for (int i = t; i < cnt; i += 256) {
        int2 rec = sorted[i];
        int b = rec.y >> 8;
        part[gbase[b] + (i - lstart[b])] = rec;
    }
}

// ---------------- phase D: per-bucket node degrees -> off[], dinv[] ----------------
__global__ __launch_bounds__(256) void bucket_nodes(const int2* __restrict__ part,
                                                    const int* __restrict__ boff,
                                                    float* __restrict__ dinv,
                                                    int* __restrict__ off, int n) {
    __shared__ int ndeg[256];
    __shared__ int ws2[4];
    int b = blockIdx.x;
    int t = threadIdx.x;
    ndeg[t] = 0;
    __syncthreads();
    int r0 = boff[b], r1 = boff[b + 1];
    for (int i = r0 + t; i < r1; i += 256)
        atomicAdd(&ndeg[part[i].y & 255], 1);
    __syncthreads();
    int deg = ndeg[t];
    int node = b * 256 + t;
    int lane = t & 63, wv = t >> 6;
    int incl = deg;
#pragma unroll
    for (int d = 1; d < 64; d <<= 1) {
        int x = __shfl_up(incl, d, 64);
        if (lane >= d) incl += x;
    }
    if (lane == 63) ws2[wv] = incl;
    __syncthreads();
    int wo = 0;
    for (int k = 0; k < wv; ++k) wo += ws2[k];
    if (node < n) {
        off[node] = r0 + wo + incl - deg;
        dinv[node] = rsqrtf((float)(deg + 1));     // +1: self-loop
    }
}

// ---------------- phase E: fine CSR fill (writes stay in bucket's 64KB window) ----------
__global__ __launch_bounds__(256) void fine_fill(const int2* __restrict__ part,
                                                 const int* __restrict__ boff,
                                                 const int* __restrict__ off,
                                                 const float* __restrict__ dinv,
                                                 int2* __restrict__ edges, int n) {
    __shared__ int cur[256];
    __shared__ int offl[256];
    __shared__ float dl[256];
    int b = blockIdx.x;
    int t = threadIdx.x;
    int node = b * 256 + t;
    cur[t] = 0;
    offl[t] = (node < n) ? off[node] : 0;
    dl[t] = (node < n) ? dinv[node] : 0.f;
    __syncthreads();
    int r0 = boff[b], r1 = boff[b + 1];
    for (int i = r0 + t; i < r1; i += 256) {
        int2 rec = part[i];
        int dloc = rec.y & 255;
        int s = rec.x;
        float w = dinv[s] * dl[dloc];
        int lpos = atomicAdd(&cur[dloc], 1);
        edges[offl[dloc] + lpos] = make_int2(s, __float_as_int(w));
    }
}

// ---------------- weight prep: WT[n][k] = bf16(W[k][n]) ----------------
__global__ void prep_w(const float* __restrict__ W, bf16* __restrict__ WT, int K, int Nout) {
    int idx = blockIdx.x * blockDim.x + threadIdx.x;
    if (idx >= K * Nout) return;
    int nn = idx / K;
    int kk = idx - nn * K;
    WT[idx] = __float2bfloat16(W[kk * Nout + nn]);
}

#define WSTRIDE 136   // bf16 elements; 272 B = 17x16 B (aligned), 2-way LDS conflict only

// ---------------- MFMA GEMM (LDS-staged WT), A fp32 [n,128] -> fp8 h ----------------
__global__ __launch_bounds__(256) void gemm128_f32A(const float* __restrict__ A,
                                                    const bf16* __restrict__ WT,
                                                    unsigned char* __restrict__ C, int n) {
    __shared__ bf16 wl[128 * WSTRIDE];   // 34 KB
    int t = threadIdx.x;
#pragma unroll
    for (int l = 0; l < 8; ++l) {
        int chunk = t + l * 256;           // 0..2047, 16B chunks
        int row = chunk >> 4, ch = chunk & 15;
        *(uint4*)&wl[row * WSTRIDE + ch * 8] = *(const uint4*)&WT[row * 128 + ch * 8];
    }
    __syncthreads();
    int wave = t >> 6, lane = t & 63;
    int m = lane & 15, q = lane >> 4;
    int row_base = blockIdx.x * 128 + wave * 32;
    int r0 = min(row_base + m, n - 1);
    int r1 = min(row_base + 16 + m, n - 1);

    f32x4 acc[2][8];
#pragma unroll
    for (int g = 0; g < 2; ++g)
#pragma unroll
        for (int c = 0; c < 8; ++c) acc[g][c] = (f32x4)(0.f);

#pragma unroll
    for (int kt = 0; kt < 4; ++kt) {
        short8 af[2];
#pragma unroll
        for (int g = 0; g < 2; ++g) {
            const float* ap = &A[(size_t)(g ? r1 : r0) * 128 + kt * 32 + q * 8];
            float4 f0 = *(const float4*)ap;
            float4 f1 = *(const float4*)(ap + 4);
            union { uint4 u; short8 s; } cv;
            cv.u.x = pack_bf16x2(f0.x, f0.y);
            cv.u.y = pack_bf16x2(f0.z, f0.w);
            cv.u.z = pack_bf16x2(f1.x, f1.y);
            cv.u.w = pack_bf16x2(f1.z, f1.w);
            af[g] = cv.s;
        }
#pragma unroll
        for (int c = 0; c < 8; ++c) {
            short8 bf = *(const short8*)&wl[(c * 16 + m) * WSTRIDE + kt * 32 + q * 8];
            acc[0][c] = __builtin_amdgcn_mfma_f32_16x16x32_bf16(af[0], bf, acc[0][c], 0, 0, 0);
            acc[1][c] = __builtin_amdgcn_mfma_f32_16x16x32_bf16(af[1], bf, acc[1][c], 0, 0, 0);
        }
    }
#pragma unroll
    for (int g = 0; g < 2; ++g)
#pragma unroll
        for (int c = 0; c < 8; ++c)
#pragma unroll
            for (int r = 0; r < 4; ++r) {
                int row = row_base + g * 16 + q * 4 + r;
                if (row < n) C[(size_t)row * 128 + c * 16 + m] = f32_to_fp8(acc[g][c][r]);
            }
}

// ---------------- MFMA GEMM (LDS-staged WT), A bf16 [n,128] -> fp8 h ----------------
__global__ __launch_bounds__(256) void gemm128_bf16A(const bf16* __restrict__ A,
                                                     const bf16* __restrict__ WT,
                                                     unsigned char* __restrict__ C, int n) {
    __shared__ bf16 wl[128 * WSTRIDE];   // 34 KB
    int t = threadIdx.x;
#pragma unroll
    for (int l = 0; l < 8; ++l) {
        int chunk = t + l * 256;
        int row = chunk >> 4, ch = chunk & 15;
        *(uint4*)&wl[row * WSTRIDE + ch * 8] = *(const uint4*)&WT[row * 128 + ch * 8];
    }
    __syncthreads();
    int wave = t >> 6, lane = t & 63;
    int m = lane & 15, q = lane >> 4;
    int row_base = blockIdx.x * 128 + wave * 32;
    int r0 = min(row_base + m, n - 1);
    int r1 = min(row_base + 16 + m, n - 1);

    f32x4 acc[2][8];
#pragma unroll
    for (int g = 0; g < 2; ++g)
#pragma unroll
        for (int c = 0; c < 8; ++c) acc[g][c] = (f32x4)(0.f);

#pragma unroll
    for (int kt = 0; kt < 4; ++kt) {
        short8 a0 = *(const short8*)&A[(size_t)r0 * 128 + kt * 32 + q * 8];
        short8 a1 = *(const short8*)&A[(size_t)r1 * 128 + kt * 32 + q * 8];
#pragma unroll
        for (int c = 0; c < 8; ++c) {
            short8 bf = *(const short8*)&wl[(c * 16 + m) * WSTRIDE + kt * 32 + q * 8];
            acc[0][c] = __builtin_amdgcn_mfma_f32_16x16x32_bf16(a0, bf, acc[0][c], 0, 0, 0);
            acc[1][c] = __builtin_amdgcn_mfma_f32_16x16x32_bf16(a1, bf, acc[1][c], 0, 0, 0);
        }
    }
#pragma unroll
    for (int g = 0; g < 2; ++g)
#pragma unroll
        for (int c = 0; c < 8; ++c)
#pragma unroll
            for (int r = 0; r < 4; ++r) {
                int row = row_base + g * 16 + q * 4 + r;
                if (row < n) C[(size_t)row * 128 + c * 16 + m] = f32_to_fp8(acc[g][c][r]);
            }
}

// ---------------- MFMA GEMM, A bf16 [n,128] x WT4 bf16 [32][128] -> bf16 [n,32] ----------------
__global__ __launch_bounds__(256) void gemm32_bf16A(const bf16* __restrict__ A,
                                                    const bf16* __restrict__ WT,
                                                    bf16* __restrict__ C, int n) {
    int wave = threadIdx.x >> 6;
    int lane = threadIdx.x & 63;
    int m = lane & 15;
    int q = lane >> 4;
    int row_base = blockIdx.x * 64 + wave * 16;
    int arow = min(row_base + m, n - 1);

    f32x4 acc[2];
    acc[0] = (f32x4)(0.f);
    acc[1] = (f32x4)(0.f);

#pragma unroll
    for (int kt = 0; kt < 4; ++kt) {
        short8 af = *(const short8*)&A[(size_t)arow * 128 + kt * 32 + q * 8];
#pragma unroll
        for (int c = 0; c < 2; ++c) {
            short8 bf = *(const short8*)&WT[(size_t)(c * 16 + m) * 128 + kt * 32 + q * 8];
            acc[c] = __builtin_amdgcn_mfma_f32_16x16x32_bf16(af, bf, acc[c], 0, 0, 0);
        }
    }
#pragma unroll
    for (int c = 0; c < 2; ++c)
#pragma unroll
        for (int r = 0; r < 4; ++r) {
            int row = row_base + q * 4 + r;
            if (row < n) C[(size_t)row * 32 + c * 16 + m] = __float2bfloat16(acc[c][r]);
        }
}

// ---------------- aggregation F=128 fp8 gather -> bf16 out (one wave/node) ----------------
// h row = 128 fp8 bytes; lane reads ushort = features lane*2, lane*2+1.
__global__ __launch_bounds__(256) void agg128(const unsigned char* __restrict__ h,
                                              const int* __restrict__ off,
                                              const int2* __restrict__ edges,
                                              const float* __restrict__ dinv,
                                              const float* __restrict__ bias,
                                              bf16* __restrict__ out, int n) {
    int wid = (blockIdx.x * blockDim.x + threadIdx.x) >> 6;
    if (wid >= n) return;
    int lane = threadIdx.x & 63;
    const unsigned short* h16 = (const unsigned short*)h;   // row = 64 ushorts
    float dl = dinv[wid];
    float sl = dl * dl;
    f32x2 f = __builtin_amdgcn_cvt_pk_f32_fp8(h16[(size_t)wid * 64 + lane], false);
    float a0 = f[0] * sl, a1 = f[1] * sl;                   // self-loop
    int i0 = off[wid], i1 = off[wid + 1];
    int i = i0;
    for (; i + 8 <= i1; i += 8) {
        int2 ee[8];
#pragma unroll
        for (int j = 0; j < 8; ++j) ee[j] = edges[i + j];
        unsigned short uu[8];
#pragma unroll
        for (int j = 0; j < 8; ++j) uu[j] = h16[(size_t)ee[j].x * 64 + lane];
#pragma unroll
        for (int j = 0; j < 8; ++j) {
            float w = __int_as_float(ee[j].y);
            f32x2 fv = __builtin_amdgcn_cvt_pk_f32_fp8(uu[j], false);
            a0 += fv[0] * w; a1 += fv[1] * w;
        }
    }
    for (; i < i1; ++i) {
        int2 e = edges[i];
        float w = __int_as_float(e.y);
        f32x2 fv = __builtin_amdgcn_cvt_pk_f32_fp8(h16[(size_t)e.x * 64 + lane], false);
        a0 += fv[0] * w; a1 += fv[1] * w;
    }
    float2 bv = *(const float2*)&bias[lane * 2];
    a0 += bv.x; a1 += bv.y;
    a0 = fmaxf(a0, 0.f); a1 = fmaxf(a1, 0.f);     // ReLU (layers 1-3 only)
    ((unsigned*)out)[(size_t)wid * 64 + lane] = pack_bf16x2(a0, a1);
}

// ---------------- aggregation F=32 bf16 gather + log_softmax -> fp32 ----------------
__global__ __launch_bounds__(256) void agg32_lsm(const bf16* __restrict__ h,
                                                 const int* __restrict__ off,
                                                 const int2* __restrict__ edges,
                                                 const float* __restrict__ dinv,
                                                 const float* __restrict__ bias,
                                                 float* __restrict__ out, int n) {
    int idx = blockIdx.x * blockDim.x + threadIdx.x;
    int node = idx >> 5;
    if (node >= n) return;
    int lane = idx & 31;
    const unsigned short* hu = (const unsigned short*)h;
    float dl = dinv[node];
    float a = __bfloat162float(h[(size_t)node * 32 + lane]) * dl * dl;
    int i0 = off[node], i1 = off[node + 1];
    int i = i0;
    for (; i + 8 <= i1; i += 8) {
        int2 ee[8];
#pragma unroll
        for (int j = 0; j < 8; ++j) ee[j] = edges[i + j];
        unsigned short vv[8];
#pragma unroll
        for (int j = 0; j < 8; ++j) vv[j] = hu[(size_t)ee[j].x * 32 + lane];
#pragma unroll
        for (int j = 0; j < 8; ++j) {
            bf16 b = *(bf16*)&vv[j];
            a += __bfloat162float(b) * __int_as_float(ee[j].y);
        }
    }
    for (; i < i1; ++i) {
        int2 e = edges[i];
        a += __bfloat162float(h[(size_t)e.x * 32 + lane]) * __int_as_float(e.y);
    }
    a += bias[lane];
    float mx = a;
    for (int d = 16; d; d >>= 1) mx = fmaxf(mx, __shfl_xor(mx, d, 32));
    float e = expf(a - mx);
    float ssum = e;
    for (int d = 16; d; d >>= 1) ssum += __shfl_xor(ssum, d, 32);
    out[(size_t)node * 32 + lane] = a - mx - logf(ssum);
}

extern "C" void kernel_launch(void* const* d_in, const int* in_sizes, int n_in,
                              void* d_out, int out_size, void* d_ws, size_t ws_size,
                              hipStream_t stream) {
    const float* x  = (const float*)d_in[0];
    const int*   ei = (const int*)d_in[1];
    const float* W1 = (const float*)d_in[2];
    const float* b1 = (const float*)d_in[3];
    const float* W2 = (const float*)d_in[4];
    const float* b2 = (const float*)d_in[5];
    const float* W3 = (const float*)d_in[6];
    const float* b3 = (const float*)d_in[7];
    const float* W4 = (const float*)d_in[8];
    const float* b4 = (const float*)d_in[9];
    float* out = (float*)d_out;

    const int N = NNODES;
    const int E = in_sizes[1] / 2;
    const int nb = (N + 255) / 256;           // 391 buckets

    char* ws = (char*)d_ws;
    size_t o = 0;
    auto alloc = [&](size_t bytes) -> void* {
        void* p = ws + o;
        o += (bytes + 255) & ~(size_t)255;
        return p;
    };
    int*   bcount  = (int*)alloc((size_t)NBMAX * 4);
    int*   boff    = (int*)alloc((size_t)(NBMAX + 1) * 4);
    int*   bcursor = (int*)alloc((size_t)NBMAX * 4);
    int*   off     = (int*)alloc((size_t)(N + 1) * 4);
    float* dinv    = (float*)alloc((size_t)N * 4);
    int2*  part    = (int2*)alloc((size_t)E * 8);      // aliased as gbuf after build
    int2*  edges   = (int2*)alloc((size_t)E * 8);
    bf16*  wt1     = (bf16*)alloc((size_t)128 * 128 * 2);
    bf16*  wt2     = (bf16*)alloc((size_t)128 * 128 * 2);
    bf16*  wt3     = (bf16*)alloc((size_t)128 * 128 * 2);
    bf16*  wt4     = (bf16*)alloc((size_t)32 * 128 * 2);
    unsigned char* hbuf = (unsigned char*)alloc((size_t)N * 128);  // fp8 L1-3 / bf16[N*32] L4
    bf16*  gbuf    = (bf16*)part;              // part dead after fine_fill; N*256B == E*8B

    const int* srcv = ei;
    const int* dstv = ei + E;

    hipMemsetAsync(bcount, 0, (size_t)NBMAX * 4, stream);

    int pblocks = (E + CH - 1) / CH;
    bucket_hist<<<pblocks, 256, 0, stream>>>(dstv, bcount, E, nb);
    bucket_scan<<<1, 512, 0, stream>>>(bcount, boff, bcursor, off, nb, N);
    partition<<<pblocks, 256, 0, stream>>>(srcv, dstv, bcursor, part, E, nb);
    bucket_nodes<<<nb, 256, 0, stream>>>(part, boff, dinv, off, N);
    fine_fill<<<nb, 256, 0, stream>>>(part, boff, off, dinv, edges, N);

    prep_w<<<64, 256, 0, stream>>>(W1, wt1, 128, 128);
    prep_w<<<64, 256, 0, stream>>>(W2, wt2, 128, 128);
    prep_w<<<64, 256, 0, stream>>>(W3, wt3, 128, 128);
    prep_w<<<16, 256, 0, stream>>>(W4, wt4, 128, 32);

    int gemm128_blocks = (N + 127) / 128;
    int gemm32_blocks = (N + 63) / 64;
    int agg128_blocks = (N + 3) / 4;
    int agg32_blocks = (N * 32 + 255) / 256;

    // Layer 1 (A fp32) -> fp8 h
    gemm128_f32A<<<gemm128_blocks, 256, 0, stream>>>(x, wt1, hbuf, N);
    agg128<<<agg128_blocks, 256, 0, stream>>>(hbuf, off, edges, dinv, b1, gbuf, N);
    // Layer 2
    gemm128_bf16A<<<gemm128_blocks, 256, 0, stream>>>(gbuf, wt2, hbuf, N);
    agg128<<<agg128_blocks, 256, 0, stream>>>(hbuf, off, edges, dinv, b2, gbuf, N);
    // Layer 3
    gemm128_bf16A<<<gemm128_blocks, 256, 0, stream>>>(gbuf, wt3, hbuf, N);
    agg128<<<agg128_blocks, 256, 0, stream>>>(hbuf, off, edges, dinv, b3, gbuf, N);
    // Layer 4: GEMM to 32 cols (bf16 h - protect final logits), then agg + log_softmax
    gemm32_bf16A<<<gemm32_blocks, 256, 0, stream>>>(gbuf, wt4, (bf16*)hbuf, N);
    agg32_lsm<<<agg32_blocks, 256, 0, stream>>>((const bf16*)hbuf, off, edges, dinv, b4, out, N);
}

// Round 9
// 594.875 us; speedup vs baseline: 2.1865x; 1.0778x over previous
//
#include <hip/hip_runtime.h>
#include <hip/hip_bf16.h>
#include <math.h>

#define NNODES 100000
#define NBMAX 512          // bucket arrays sized to 512; actual nb = ceil(N/256) = 391
#define CH 8192            // edges per partition block

typedef __hip_bfloat16 bf16;
typedef __attribute__((ext_vector_type(8))) short short8;   // bf16x8 MFMA A/B frag
typedef __attribute__((ext_vector_type(4))) float f32x4;    // MFMA C/D frag
typedef __attribute__((ext_vector_type(2))) float f32x2;

__device__ inline unsigned pack_bf16x2(float a, float b) {
    __hip_bfloat162 p;
    p.x = __float2bfloat16(a);
    p.y = __float2bfloat16(b);
    return *(unsigned*)&p;
}

__device__ inline unsigned char f32_to_fp8(float v) {
    int p = __builtin_amdgcn_cvt_pk_fp8_f32(v, v, 0, false);   // OCP e4m3 on gfx950
    return (unsigned char)(p & 0xff);
}

// ---------------- phase A: bucket histogram (bucket = dst >> 8) ----------------
__global__ __launch_bounds__(256) void bucket_hist(const int* __restrict__ dst,
                                                   int* __restrict__ bcount, int E, int nb) {
    __shared__ int hist[NBMAX];
    int t = threadIdx.x;
    for (int i = t; i < NBMAX; i += 256) hist[i] = 0;
    __syncthreads();
    int e0 = blockIdx.x * CH;
#pragma unroll
    for (int k = 0; k < 32; ++k) {
        int e = e0 + t + k * 256;
        if (e < E) atomicAdd(&hist[dst[e] >> 8], 1);
    }
    __syncthreads();
    for (int i = t; i < nb; i += 256)
        if (hist[i]) atomicAdd(&bcount[i], hist[i]);
}

// ---------------- phase B: scan bucket counts (1 block, 512 threads) ----------------
__global__ __launch_bounds__(512) void bucket_scan(const int* __restrict__ bcount,
                                                   int* __restrict__ boff,
                                                   int* __restrict__ bcursor,
                                                   int* __restrict__ off, int nb, int n) {
    __shared__ int wsum[8];
    int t = threadIdx.x;
    int v = (t < nb) ? bcount[t] : 0;
    int lane = t & 63, wv = t >> 6;
    int incl = v;
#pragma unroll
    for (int d = 1; d < 64; d <<= 1) {
        int x = __shfl_up(incl, d, 64);
        if (lane >= d) incl += x;
    }
    if (lane == 63) wsum[wv] = incl;
    __syncthreads();
    int wo = 0;
    for (int k = 0; k < wv; ++k) wo += wsum[k];
    int excl = wo + incl - v;
    if (t <= nb) {
        boff[t] = excl;
        if (t < nb) bcursor[t] = excl;
    }
    if (t == nb) off[n] = excl;      // grand total == E
}

// ---------------- phase C: partition edges into bucket-contiguous ranges ----------------
__global__ __launch_bounds__(256) void partition(const int* __restrict__ src,
                                                 const int* __restrict__ dst,
                                                 int* __restrict__ bcursor,
                                                 int2* __restrict__ part, int E, int nb) {
    __shared__ int hist[NBMAX];
    __shared__ int lstart[NBMAX];
    __shared__ int gbase[NBMAX];
    __shared__ int cursor[NBMAX];
    __shared__ int2 sorted[CH];
    int t = threadIdx.x;
    int e0 = blockIdx.x * CH;
    for (int i = t; i < NBMAX; i += 256) hist[i] = 0;
    __syncthreads();
    int mys[32], myd[32];
#pragma unroll
    for (int k = 0; k < 32; ++k) {
        int e = e0 + t + k * 256;
        int s = 0, d = -1;
        if (e < E) { s = src[e]; d = dst[e]; }
        mys[k] = s; myd[k] = d;
        if (d >= 0) atomicAdd(&hist[d >> 8], 1);
    }
    __syncthreads();
    if (t < 64) {
        int base = t * 8;
        int tmp[8];
        int sum = 0;
#pragma unroll
        for (int j = 0; j < 8; ++j) { tmp[j] = hist[base + j]; sum += tmp[j]; }
        int incl = sum;
#pragma unroll
        for (int d = 1; d < 64; d <<= 1) {
            int x = __shfl_up(incl, d, 64);
            if (t >= d) incl += x;
        }
        int excl = incl - sum;
#pragma unroll
        for (int j = 0; j < 8; ++j) {
            lstart[base + j] = excl;
            cursor[base + j] = excl;
            excl += tmp[j];
        }
    }
    __syncthreads();
    for (int i = t; i < nb; i += 256) {
        int c = hist[i];
        gbase[i] = c ? atomicAdd(&bcursor[i], c) : 0;
    }
    __syncthreads();
#pragma unroll
    for (int k = 0; k < 32; ++k) {
        int d = myd[k];
        if (d >= 0) {
            int lpos = atomicAdd(&cursor[d >> 8], 1);
            sorted[lpos] = make_int2(mys[k], d);
        }
    }
    __syncthreads();
    int cnt = min(CH, E - e0);
    for (int i = t; i < cnt; i += 256) {
        int2 rec = sorted[i];
        int b = rec.y >> 8;
        part[gbase[b] + (i - lstart[b])] = rec;
    }
}

// ---------------- phase D: per-bucket node degrees -> off[], dinv[] ----------------
__global__ __launch_bounds__(256) void bucket_nodes(const int2* __restrict__ part,
                                                    const int* __restrict__ boff,
                                                    float* __restrict__ dinv,
                                                    int* __restrict__ off, int n) {
    __shared__ int ndeg[256];
    __shared__ int ws2[4];
    int b = blockIdx.x;
    int t = threadIdx.x;
    ndeg[t] = 0;
    __syncthreads();
    int r0 = boff[b], r1 = boff[b + 1];
    for (int i = r0 + t; i < r1; i += 256)
        atomicAdd(&ndeg[part[i].y & 255], 1);
    __syncthreads();
    int deg = ndeg[t];
    int node = b * 256 + t;
    int lane = t & 63, wv = t >> 6;
    int incl = deg;
#pragma unroll
    for (int d = 1; d < 64; d <<= 1) {
        int x = __shfl_up(incl, d, 64);
        if (lane >= d) incl += x;
    }
    if (lane == 63) ws2[wv] = incl;
    __syncthreads();
    int wo = 0;
    for (int k = 0; k < wv; ++k) wo += ws2[k];
    if (node < n) {
        off[node] = r0 + wo + incl - deg;
        dinv[node] = rsqrtf((float)(deg + 1));     // +1: self-loop
    }
}

// ---------------- phase E: fine CSR fill (int src only; norm folded into h) ----------
__global__ __launch_bounds__(256) void fine_fill(const int2* __restrict__ part,
                                                 const int* __restrict__ boff,
                                                 const int* __restrict__ off,
                                                 int* __restrict__ edges, int n) {
    __shared__ int cur[256];
    __shared__ int offl[256];
    int b = blockIdx.x;
    int t = threadIdx.x;
    int node = b * 256 + t;
    cur[t] = 0;
    offl[t] = (node < n) ? off[node] : 0;
    __syncthreads();
    int r0 = boff[b], r1 = boff[b + 1];
    for (int i = r0 + t; i < r1; i += 256) {
        int2 rec = part[i];
        int dloc = rec.y & 255;
        int lpos = atomicAdd(&cur[dloc], 1);
        edges[offl[dloc] + lpos] = rec.x;
    }
}

// ---------------- weight prep: WT[n][k] = bf16(W[k][n]) ----------------
__global__ void prep_w(const float* __restrict__ W, bf16* __restrict__ WT, int K, int Nout) {
    int idx = blockIdx.x * blockDim.x + threadIdx.x;
    if (idx >= K * Nout) return;
    int nn = idx / K;
    int kk = idx - nn * K;
    WT[idx] = __float2bfloat16(W[kk * Nout + nn]);
}

#define WSTRIDE 136   // bf16 elements; 272 B = 17x16 B (aligned), 2-way LDS conflict only

// ---------------- MFMA GEMM (LDS-staged WT), A fp32 [n,128] -> fp8 h' = h*dinv[row] ----
__global__ __launch_bounds__(256) void gemm128_f32A(const float* __restrict__ A,
                                                    const bf16* __restrict__ WT,
                                                    const float* __restrict__ dinv,
                                                    unsigned char* __restrict__ C, int n) {
    __shared__ bf16 wl[128 * WSTRIDE];   // 34 KB
    int t = threadIdx.x;
#pragma unroll
    for (int l = 0; l < 8; ++l) {
        int chunk = t + l * 256;           // 0..2047, 16B chunks
        int row = chunk >> 4, ch = chunk & 15;
        *(uint4*)&wl[row * WSTRIDE + ch * 8] = *(const uint4*)&WT[row * 128 + ch * 8];
    }
    __syncthreads();
    int wave = t >> 6, lane = t & 63;
    int m = lane & 15, q = lane >> 4;
    int row_base = blockIdx.x * 128 + wave * 32;
    int r0 = min(row_base + m, n - 1);
    int r1 = min(row_base + 16 + m, n - 1);

    f32x4 acc[2][8];
#pragma unroll
    for (int g = 0; g < 2; ++g)
#pragma unroll
        for (int c = 0; c < 8; ++c) acc[g][c] = (f32x4)(0.f);

#pragma unroll
    for (int kt = 0; kt < 4; ++kt) {
        short8 af[2];
#pragma unroll
        for (int g = 0; g < 2; ++g) {
            const float* ap = &A[(size_t)(g ? r1 : r0) * 128 + kt * 32 + q * 8];
            float4 f0 = *(const float4*)ap;
            float4 f1 = *(const float4*)(ap + 4);
            union { uint4 u; short8 s; } cv;
            cv.u.x = pack_bf16x2(f0.x, f0.y);
            cv.u.y = pack_bf16x2(f0.z, f0.w);
            cv.u.z = pack_bf16x2(f1.x, f1.y);
            cv.u.w = pack_bf16x2(f1.z, f1.w);
            af[g] = cv.s;
        }
#pragma unroll
        for (int c = 0; c < 8; ++c) {
            short8 bf = *(const short8*)&wl[(c * 16 + m) * WSTRIDE + kt * 32 + q * 8];
            acc[0][c] = __builtin_amdgcn_mfma_f32_16x16x32_bf16(af[0], bf, acc[0][c], 0, 0, 0);
            acc[1][c] = __builtin_amdgcn_mfma_f32_16x16x32_bf16(af[1], bf, acc[1][c], 0, 0, 0);
        }
    }
    float dv[2][4];
#pragma unroll
    for (int g = 0; g < 2; ++g)
#pragma unroll
        for (int r = 0; r < 4; ++r) {
            int row = row_base + g * 16 + q * 4 + r;
            dv[g][r] = (row < n) ? dinv[row] : 0.f;
        }
#pragma unroll
    for (int g = 0; g < 2; ++g)
#pragma unroll
        for (int c = 0; c < 8; ++c)
#pragma unroll
            for (int r = 0; r < 4; ++r) {
                int row = row_base + g * 16 + q * 4 + r;
                if (row < n) C[(size_t)row * 128 + c * 16 + m] = f32_to_fp8(acc[g][c][r] * dv[g][r]);
            }
}

// ---------------- MFMA GEMM (LDS-staged WT), A bf16 [n,128] -> fp8 h' ----------------
__global__ __launch_bounds__(256) void gemm128_bf16A(const bf16* __restrict__ A,
                                                     const bf16* __restrict__ WT,
                                                     const float* __restrict__ dinv,
                                                     unsigned char* __restrict__ C, int n) {
    __shared__ bf16 wl[128 * WSTRIDE];   // 34 KB
    int t = threadIdx.x;
#pragma unroll
    for (int l = 0; l < 8; ++l) {
        int chunk = t + l * 256;
        int row = chunk >> 4, ch = chunk & 15;
        *(uint4*)&wl[row * WSTRIDE + ch * 8] = *(const uint4*)&WT[row * 128 + ch * 8];
    }
    __syncthreads();
    int wave = t >> 6, lane = t & 63;
    int m = lane & 15, q = lane >> 4;
    int row_base = blockIdx.x * 128 + wave * 32;
    int r0 = min(row_base + m, n - 1);
    int r1 = min(row_base + 16 + m, n - 1);

    f32x4 acc[2][8];
#pragma unroll
    for (int g = 0; g < 2; ++g)
#pragma unroll
        for (int c = 0; c < 8; ++c) acc[g][c] = (f32x4)(0.f);

#pragma unroll
    for (int kt = 0; kt < 4; ++kt) {
        short8 a0 = *(const short8*)&A[(size_t)r0 * 128 + kt * 32 + q * 8];
        short8 a1 = *(const short8*)&A[(size_t)r1 * 128 + kt * 32 + q * 8];
#pragma unroll
        for (int c = 0; c < 8; ++c) {
            short8 bf = *(const short8*)&wl[(c * 16 + m) * WSTRIDE + kt * 32 + q * 8];
            acc[0][c] = __builtin_amdgcn_mfma_f32_16x16x32_bf16(a0, bf, acc[0][c], 0, 0, 0);
            acc[1][c] = __builtin_amdgcn_mfma_f32_16x16x32_bf16(a1, bf, acc[1][c], 0, 0, 0);
        }
    }
    float dv[2][4];
#pragma unroll
    for (int g = 0; g < 2; ++g)
#pragma unroll
        for (int r = 0; r < 4; ++r) {
            int row = row_base + g * 16 + q * 4 + r;
            dv[g][r] = (row < n) ? dinv[row] : 0.f;
        }
#pragma unroll
    for (int g = 0; g < 2; ++g)
#pragma unroll
        for (int c = 0; c < 8; ++c)
#pragma unroll
            for (int r = 0; r < 4; ++r) {
                int row = row_base + g * 16 + q * 4 + r;
                if (row < n) C[(size_t)row * 128 + c * 16 + m] = f32_to_fp8(acc[g][c][r] * dv[g][r]);
            }
}

// ---------------- MFMA GEMM, A bf16 [n,128] x WT4 [32][128] -> bf16 h'4 = h4*dinv ------
__global__ __launch_bounds__(256) void gemm32_bf16A(const bf16* __restrict__ A,
                                                    const bf16* __restrict__ WT,
                                                    const float* __restrict__ dinv,
                                                    bf16* __restrict__ C, int n) {
    int wave = threadIdx.x >> 6;
    int lane = threadIdx.x & 63;
    int m = lane & 15;
    int q = lane >> 4;
    int row_base = blockIdx.x * 64 + wave * 16;
    int arow = min(row_base + m, n - 1);

    f32x4 acc[2];
    acc[0] = (f32x4)(0.f);
    acc[1] = (f32x4)(0.f);

#pragma unroll
    for (int kt = 0; kt < 4; ++kt) {
        short8 af = *(const short8*)&A[(size_t)arow * 128 + kt * 32 + q * 8];
#pragma unroll
        for (int c = 0; c < 2; ++c) {
            short8 bf = *(const short8*)&WT[(size_t)(c * 16 + m) * 128 + kt * 32 + q * 8];
            acc[c] = __builtin_amdgcn_mfma_f32_16x16x32_bf16(af, bf, acc[c], 0, 0, 0);
        }
    }
    float dv[4];
#pragma unroll
    for (int r = 0; r < 4; ++r) {
        int row = row_base + q * 4 + r;
        dv[r] = (row < n) ? dinv[row] : 0.f;
    }
#pragma unroll
    for (int c = 0; c < 2; ++c)
#pragma unroll
        for (int r = 0; r < 4; ++r) {
            int row = row_base + q * 4 + r;
            if (row < n) C[(size_t)row * 32 + c * 16 + m] = __float2bfloat16(acc[c][r] * dv[r]);
        }
}

// ---------------- aggregation F=128 fp8 gather, pre-scaled rows: pure sum --------------
// out[d] = relu(dinv[d] * (sum_src h'[src] + h'[d]) + bias)
__global__ __launch_bounds__(256) void agg128(const unsigned char* __restrict__ h,
                                              const int* __restrict__ off,
                                              const int* __restrict__ edges,
                                              const float* __restrict__ dinv,
                                              const float* __restrict__ bias,
                                              bf16* __restrict__ out, int n) {
    int wid = (blockIdx.x * blockDim.x + threadIdx.x) >> 6;
    if (wid >= n) return;
    int lane = threadIdx.x & 63;
    const unsigned short* h16 = (const unsigned short*)h;   // row = 64 ushorts
    f32x2 sf = __builtin_amdgcn_cvt_pk_f32_fp8(h16[(size_t)wid * 64 + lane], false);
    float a0 = sf[0], a1 = sf[1];                            // self-loop h'[d]
    int i0 = off[wid], i1 = off[wid + 1];
    int i = i0;
    for (; i + 8 <= i1; i += 8) {
        unsigned short uu[8];
#pragma unroll
        for (int j = 0; j < 8; ++j) {
            int s = __builtin_amdgcn_readfirstlane(edges[i + j]);   // wave-uniform -> SALU addr
            uu[j] = h16[(size_t)s * 64 + lane];
        }
#pragma unroll
        for (int j = 0; j < 8; ++j) {
            f32x2 fv = __builtin_amdgcn_cvt_pk_f32_fp8(uu[j], false);
            a0 += fv[0]; a1 += fv[1];
        }
    }
    for (; i < i1; ++i) {
        int s = __builtin_amdgcn_readfirstlane(edges[i]);
        f32x2 fv = __builtin_amdgcn_cvt_pk_f32_fp8(h16[(size_t)s * 64 + lane], false);
        a0 += fv[0]; a1 += fv[1];
    }
    float dl = dinv[wid];
    float2 bv = *(const float2*)&bias[lane * 2];
    a0 = fmaxf(a0 * dl + bv.x, 0.f);
    a1 = fmaxf(a1 * dl + bv.y, 0.f);
    ((unsigned*)out)[(size_t)wid * 64 + lane] = pack_bf16x2(a0, a1);
}

// ---------------- aggregation F=32 bf16 gather + log_softmax -> fp32 ----------------
__global__ __launch_bounds__(256) void agg32_lsm(const bf16* __restrict__ h,
                                                 const int* __restrict__ off,
                                                 const int* __restrict__ edges,
                                                 const float* __restrict__ dinv,
                                                 const float* __restrict__ bias,
                                                 float* __restrict__ out, int n) {
    int idx = blockIdx.x * blockDim.x + threadIdx.x;
    int node = idx >> 5;
    if (node >= n) return;
    int lane = idx & 31;
    const unsigned short* hu = (const unsigned short*)h;
    bf16 selfv = h[(size_t)node * 32 + lane];
    float a = __bfloat162float(selfv);                      // self-loop h'4[d]
    int i0 = off[node], i1 = off[node + 1];
    int i = i0;
    for (; i + 8 <= i1; i += 8) {
        int ee[8];
#pragma unroll
        for (int j = 0; j < 8; ++j) ee[j] = edges[i + j];
        unsigned short vv[8];
#pragma unroll
        for (int j = 0; j < 8; ++j) vv[j] = hu[(size_t)ee[j] * 32 + lane];
#pragma unroll
        for (int j = 0; j < 8; ++j) {
            bf16 b = *(bf16*)&vv[j];
            a += __bfloat162float(b);
        }
    }
    for (; i < i1; ++i)
        a += __bfloat162float(h[(size_t)edges[i] * 32 + lane]);
    a = a * dinv[node] + bias[lane];
    float mx = a;
    for (int d = 16; d; d >>= 1) mx = fmaxf(mx, __shfl_xor(mx, d, 32));
    float e = expf(a - mx);
    float ssum = e;
    for (int d = 16; d; d >>= 1) ssum += __shfl_xor(ssum, d, 32);
    out[(size_t)node * 32 + lane] = a - mx - logf(ssum);
}

extern "C" void kernel_launch(void* const* d_in, const int* in_sizes, int n_in,
                              void* d_out, int out_size, void* d_ws, size_t ws_size,
                              hipStream_t stream) {
    const float* x  = (const float*)d_in[0];
    const int*   ei = (const int*)d_in[1];
    const float* W1 = (const float*)d_in[2];
    const float* b1 = (const float*)d_in[3];
    const float* W2 = (const float*)d_in[4];
    const float* b2 = (const float*)d_in[5];
    const float* W3 = (const float*)d_in[6];
    const float* b3 = (const float*)d_in[7];
    const float* W4 = (const float*)d_in[8];
    const float* b4 = (const float*)d_in[9];
    float* out = (float*)d_out;

    const int N = NNODES;
    const int E = in_sizes[1] / 2;
    const int nb = (N + 255) / 256;           // 391 buckets

    char* ws = (char*)d_ws;
    size_t o = 0;
    auto alloc = [&](size_t bytes) -> void* {
        void* p = ws + o;
        o += (bytes + 255) & ~(size_t)255;
        return p;
    };
    int*   bcount  = (int*)alloc((size_t)NBMAX * 4);
    int*   boff    = (int*)alloc((size_t)(NBMAX + 1) * 4);
    int*   bcursor = (int*)alloc((size_t)NBMAX * 4);
    int*   off     = (int*)alloc((size_t)(N + 1) * 4);
    float* dinv    = (float*)alloc((size_t)N * 4);
    int2*  part    = (int2*)alloc((size_t)E * 8);      // aliased as gbuf after build
    int*   edges   = (int*)alloc((size_t)E * 4);
    bf16*  wt1     = (bf16*)alloc((size_t)128 * 128 * 2);
    bf16*  wt2     = (bf16*)alloc((size_t)128 * 128 * 2);
    bf16*  wt3     = (bf16*)alloc((size_t)128 * 128 * 2);
    bf16*  wt4     = (bf16*)alloc((size_t)32 * 128 * 2);
    unsigned char* hbuf = (unsigned char*)alloc((size_t)N * 128);  // fp8 L1-3 / bf16[N*32] L4
    bf16*  gbuf    = (bf16*)part;              // part dead after fine_fill; N*256B == E*8B

    const int* srcv = ei;
    const int* dstv = ei + E;

    hipMemsetAsync(bcount, 0, (size_t)NBMAX * 4, stream);

    int pblocks = (E + CH - 1) / CH;
    bucket_hist<<<pblocks, 256, 0, stream>>>(dstv, bcount, E, nb);
    bucket_scan<<<1, 512, 0, stream>>>(bcount, boff, bcursor, off, nb, N);
    partition<<<pblocks, 256, 0, stream>>>(srcv, dstv, bcursor, part, E, nb);
    bucket_nodes<<<nb, 256, 0, stream>>>(part, boff, dinv, off, N);
    fine_fill<<<nb, 256, 0, stream>>>(part, boff, off, edges, N);

    prep_w<<<64, 256, 0, stream>>>(W1, wt1, 128, 128);
    prep_w<<<64, 256, 0, stream>>>(W2, wt2, 128, 128);
    prep_w<<<64, 256, 0, stream>>>(W3, wt3, 128, 128);
    prep_w<<<16, 256, 0, stream>>>(W4, wt4, 128, 32);

    int gemm128_blocks = (N + 127) / 128;
    int gemm32_blocks = (N + 63) / 64;
    int agg128_blocks = (N + 3) / 4;
    int agg32_blocks = (N * 32 + 255) / 256;

    // Layer 1 (A fp32) -> fp8 h' (pre-scaled by dinv)
    gemm128_f32A<<<gemm128_blocks, 256, 0, stream>>>(x, wt1, dinv, hbuf, N);
    agg128<<<agg128_blocks, 256, 0, stream>>>(hbuf, off, edges, dinv, b1, gbuf, N);
    // Layer 2
    gemm128_bf16A<<<gemm128_blocks, 256, 0, stream>>>(gbuf, wt2, dinv, hbuf, N);
    agg128<<<agg128_blocks, 256, 0, stream>>>(hbuf, off, edges, dinv, b2, gbuf, N);
    // Layer 3
    gemm128_bf16A<<<gemm128_blocks, 256, 0, stream>>>(gbuf, wt3, dinv, hbuf, N);
    agg128<<<agg128_blocks, 256, 0, stream>>>(hbuf, off, edges, dinv, b3, gbuf, N);
    // Layer 4: GEMM to 32 cols (bf16 h'4 - protect final logits), then agg + log_softmax
    gemm32_bf16A<<<gemm32_blocks, 256, 0, stream>>>(gbuf, wt4, dinv, (bf16*)hbuf, N);
    agg32_lsm<<<agg32_blocks, 256, 0, stream>>>((const bf16*)hbuf, off, edges, dinv, b4, out, N);
}

// Round 10
// 567.420 us; speedup vs baseline: 2.2923x; 1.0484x over previous
//
#include <hip/hip_runtime.h>
#include <hip/hip_bf16.h>
#include <math.h>

#define NNODES 100000
#define NBMAX 512          // bucket arrays sized to 512; actual nb = ceil(N/256) = 391
#define CH 8192            // edges per partition block

typedef __hip_bfloat16 bf16;
typedef __attribute__((ext_vector_type(8))) short short8;   // bf16x8 MFMA A/B frag
typedef __attribute__((ext_vector_type(4))) float f32x4;    // MFMA C/D frag
typedef __attribute__((ext_vector_type(2))) float f32x2;

__device__ inline unsigned pack_bf16x2(float a, float b) {
    __hip_bfloat162 p;
    p.x = __float2bfloat16(a);
    p.y = __float2bfloat16(b);
    return *(unsigned*)&p;
}

__device__ inline unsigned char f32_to_fp8(float v) {
    int p = __builtin_amdgcn_cvt_pk_fp8_f32(v, v, 0, false);   // OCP e4m3 on gfx950
    return (unsigned char)(p & 0xff);
}

// ---------------- phase A: bucket histogram (bucket = dst >> 8) ----------------
__global__ __launch_bounds__(256) void bucket_hist(const int* __restrict__ dst,
                                                   int* __restrict__ bcount, int E, int nb) {
    __shared__ int hist[NBMAX];
    int t = threadIdx.x;
    for (int i = t; i < NBMAX; i += 256) hist[i] = 0;
    __syncthreads();
    int e0 = blockIdx.x * CH;
#pragma unroll
    for (int k = 0; k < 32; ++k) {
        int e = e0 + t + k * 256;
        if (e < E) atomicAdd(&hist[dst[e] >> 8], 1);
    }
    __syncthreads();
    for (int i = t; i < nb; i += 256)
        if (hist[i]) atomicAdd(&bcount[i], hist[i]);
}

// ---------------- phase B: scan bucket counts (1 block, 512 threads) ----------------
__global__ __launch_bounds__(512) void bucket_scan(const int* __restrict__ bcount,
                                                   int* __restrict__ boff,
                                                   int* __restrict__ bcursor,
                                                   int* __restrict__ off, int nb, int n) {
    __shared__ int wsum[8];
    int t = threadIdx.x;
    int v = (t < nb) ? bcount[t] : 0;
    int lane = t & 63, wv = t >> 6;
    int incl = v;
#pragma unroll
    for (int d = 1; d < 64; d <<= 1) {
        int x = __shfl_up(incl, d, 64);
        if (lane >= d) incl += x;
    }
    if (lane == 63) wsum[wv] = incl;
    __syncthreads();
    int wo = 0;
    for (int k = 0; k < wv; ++k) wo += wsum[k];
    int excl = wo + incl - v;
    if (t <= nb) {
        boff[t] = excl;
        if (t < nb) bcursor[t] = excl;
    }
    if (t == nb) off[n] = excl;      // grand total == E
}

// ---------------- phase C: partition edges into bucket-contiguous ranges ----------------
__global__ __launch_bounds__(256) void partition(const int* __restrict__ src,
                                                 const int* __restrict__ dst,
                                                 int* __restrict__ bcursor,
                                                 int2* __restrict__ part, int E, int nb) {
    __shared__ int hist[NBMAX];
    __shared__ int lstart[NBMAX];
    __shared__ int gbase[NBMAX];
    __shared__ int cursor[NBMAX];
    __shared__ int2 sorted[CH];
    int t = threadIdx.x;
    int e0 = blockIdx.x * CH;
    for (int i = t; i < NBMAX; i += 256) hist[i] = 0;
    __syncthreads();
    int mys[32], myd[32];
#pragma unroll
    for (int k = 0; k < 32; ++k) {
        int e = e0 + t + k * 256;
        int s = 0, d = -1;
        if (e < E) { s = src[e]; d = dst[e]; }
        mys[k] = s; myd[k] = d;
        if (d >= 0) atomicAdd(&hist[d >> 8], 1);
    }
    __syncthreads();
    if (t < 64) {
        int base = t * 8;
        int tmp[8];
        int sum = 0;
#pragma unroll
        for (int j = 0; j < 8; ++j) { tmp[j] = hist[base + j]; sum += tmp[j]; }
        int incl = sum;
#pragma unroll
        for (int d = 1; d < 64; d <<= 1) {
            int x = __shfl_up(incl, d, 64);
            if (t >= d) incl += x;
        }
        int excl = incl - sum;
#pragma unroll
        for (int j = 0; j < 8; ++j) {
            lstart[base + j] = excl;
            cursor[base + j] = excl;
            excl += tmp[j];
        }
    }
    __syncthreads();
    for (int i = t; i < nb; i += 256) {
        int c = hist[i];
        gbase[i] = c ? atomicAdd(&bcursor[i], c) : 0;
    }
    __syncthreads();
#pragma unroll
    for (int k = 0; k < 32; ++k) {
        int d = myd[k];
        if (d >= 0) {
            int lpos = atomicAdd(&cursor[d >> 8], 1);
            sorted[lpos] = make_int2(mys[k], d);
        }
    }
    __syncthreads();
    int cnt = min(CH, E - e0);
    for (int i = t; i < cnt; i += 256) {
        int2 rec = sorted[i];
        int b = rec.y >> 8;
        part[gbase[b] + (i - lstart[b])] = rec;
    }
}

// ---------------- phase D: per-bucket node degrees -> off[], dinv[] ----------------
__global__ __launch_bounds__(256) void bucket_nodes(const int2* __restrict__ part,
                                                    const int* __restrict__ boff,
                                                    float* __restrict__ dinv,
                                                    int* __restrict__ off, int n) {
    __shared__ int ndeg[256];
    __shared__ int ws2[4];
    int b = blockIdx.x;
    int t = threadIdx.x;
    ndeg[t] = 0;
    __syncthreads();
    int r0 = boff[b], r1 = boff[b + 1];
    for (int i = r0 + t; i < r1; i += 256)
        atomicAdd(&ndeg[part[i].y & 255], 1);
    __syncthreads();
    int deg = ndeg[t];
    int node = b * 256 + t;
    int lane = t & 63, wv = t >> 6;
    int incl = deg;
#pragma unroll
    for (int d = 1; d < 64; d <<= 1) {
        int x = __shfl_up(incl, d, 64);
        if (lane >= d) incl += x;
    }
    if (lane == 63) ws2[wv] = incl;
    __syncthreads();
    int wo = 0;
    for (int k = 0; k < wv; ++k) wo += ws2[k];
    if (node < n) {
        off[node] = r0 + wo + incl - deg;
        dinv[node] = rsqrtf((float)(deg + 1));     // +1: self-loop
    }
}

// ---------------- phase E: fine CSR fill (int src only; norm folded into h) ----------
__global__ __launch_bounds__(256) void fine_fill(const int2* __restrict__ part,
                                                 const int* __restrict__ boff,
                                                 const int* __restrict__ off,
                                                 int* __restrict__ edges, int n) {
    __shared__ int cur[256];
    __shared__ int offl[256];
    int b = blockIdx.x;
    int t = threadIdx.x;
    int node = b * 256 + t;
    cur[t] = 0;
    offl[t] = (node < n) ? off[node] : 0;
    __syncthreads();
    int r0 = boff[b], r1 = boff[b + 1];
    for (int i = r0 + t; i < r1; i += 256) {
        int2 rec = part[i];
        int dloc = rec.y & 255;
        int lpos = atomicAdd(&cur[dloc], 1);
        edges[offl[dloc] + lpos] = rec.x;
    }
}

// ---------------- weight prep: WT[n][k] = bf16(W[k][n]) ----------------
__global__ void prep_w(const float* __restrict__ W, bf16* __restrict__ WT, int K, int Nout) {
    int idx = blockIdx.x * blockDim.x + threadIdx.x;
    if (idx >= K * Nout) return;
    int nn = idx / K;
    int kk = idx - nn * K;
    WT[idx] = __float2bfloat16(W[kk * Nout + nn]);
}

#define WSTRIDE 136   // bf16 elements; 272 B = 17x16 B (aligned), 2-way LDS conflict only

// ---------------- MFMA GEMM (LDS-staged WT), A fp32 [n,128] -> fp8 h' = h*dinv[row] ----
__global__ __launch_bounds__(256) void gemm128_f32A(const float* __restrict__ A,
                                                    const bf16* __restrict__ WT,
                                                    const float* __restrict__ dinv,
                                                    unsigned char* __restrict__ C, int n) {
    __shared__ bf16 wl[128 * WSTRIDE];   // 34 KB
    int t = threadIdx.x;
#pragma unroll
    for (int l = 0; l < 8; ++l) {
        int chunk = t + l * 256;           // 0..2047, 16B chunks
        int row = chunk >> 4, ch = chunk & 15;
        *(uint4*)&wl[row * WSTRIDE + ch * 8] = *(const uint4*)&WT[row * 128 + ch * 8];
    }
    __syncthreads();
    int wave = t >> 6, lane = t & 63;
    int m = lane & 15, q = lane >> 4;
    int row_base = blockIdx.x * 128 + wave * 32;
    int r0 = min(row_base + m, n - 1);
    int r1 = min(row_base + 16 + m, n - 1);

    f32x4 acc[2][8];
#pragma unroll
    for (int g = 0; g < 2; ++g)
#pragma unroll
        for (int c = 0; c < 8; ++c) acc[g][c] = (f32x4)(0.f);

#pragma unroll
    for (int kt = 0; kt < 4; ++kt) {
        short8 af[2];
#pragma unroll
        for (int g = 0; g < 2; ++g) {
            const float* ap = &A[(size_t)(g ? r1 : r0) * 128 + kt * 32 + q * 8];
            float4 f0 = *(const float4*)ap;
            float4 f1 = *(const float4*)(ap + 4);
            union { uint4 u; short8 s; } cv;
            cv.u.x = pack_bf16x2(f0.x, f0.y);
            cv.u.y = pack_bf16x2(f0.z, f0.w);
            cv.u.z = pack_bf16x2(f1.x, f1.y);
            cv.u.w = pack_bf16x2(f1.z, f1.w);
            af[g] = cv.s;
        }
#pragma unroll
        for (int c = 0; c < 8; ++c) {
            short8 bf = *(const short8*)&wl[(c * 16 + m) * WSTRIDE + kt * 32 + q * 8];
            acc[0][c] = __builtin_amdgcn_mfma_f32_16x16x32_bf16(af[0], bf, acc[0][c], 0, 0, 0);
            acc[1][c] = __builtin_amdgcn_mfma_f32_16x16x32_bf16(af[1], bf, acc[1][c], 0, 0, 0);
        }
    }
    float dv[2][4];
#pragma unroll
    for (int g = 0; g < 2; ++g)
#pragma unroll
        for (int r = 0; r < 4; ++r) {
            int row = row_base + g * 16 + q * 4 + r;
            dv[g][r] = (row < n) ? dinv[row] : 0.f;
        }
#pragma unroll
    for (int g = 0; g < 2; ++g)
#pragma unroll
        for (int c = 0; c < 8; ++c)
#pragma unroll
            for (int r = 0; r < 4; ++r) {
                int row = row_base + g * 16 + q * 4 + r;
                if (row < n) C[(size_t)row * 128 + c * 16 + m] = f32_to_fp8(acc[g][c][r] * dv[g][r]);
            }
}

// ---------------- MFMA GEMM (LDS-staged WT), A bf16 [n,128] -> fp8 h' ----------------
__global__ __launch_bounds__(256) void gemm128_bf16A(const bf16* __restrict__ A,
                                                     const bf16* __restrict__ WT,
                                                     const float* __restrict__ dinv,
                                                     unsigned char* __restrict__ C, int n) {
    __shared__ bf16 wl[128 * WSTRIDE];   // 34 KB
    int t = threadIdx.x;
#pragma unroll
    for (int l = 0; l < 8; ++l) {
        int chunk = t + l * 256;
        int row = chunk >> 4, ch = chunk & 15;
        *(uint4*)&wl[row * WSTRIDE + ch * 8] = *(const uint4*)&WT[row * 128 + ch * 8];
    }
    __syncthreads();
    int wave = t >> 6, lane = t & 63;
    int m = lane & 15, q = lane >> 4;
    int row_base = blockIdx.x * 128 + wave * 32;
    int r0 = min(row_base + m, n - 1);
    int r1 = min(row_base + 16 + m, n - 1);

    f32x4 acc[2][8];
#pragma unroll
    for (int g = 0; g < 2; ++g)
#pragma unroll
        for (int c = 0; c < 8; ++c) acc[g][c] = (f32x4)(0.f);

#pragma unroll
    for (int kt = 0; kt < 4; ++kt) {
        short8 a0 = *(const short8*)&A[(size_t)r0 * 128 + kt * 32 + q * 8];
        short8 a1 = *(const short8*)&A[(size_t)r1 * 128 + kt * 32 + q * 8];
#pragma unroll
        for (int c = 0; c < 8; ++c) {
            short8 bf = *(const short8*)&wl[(c * 16 + m) * WSTRIDE + kt * 32 + q * 8];
            acc[0][c] = __builtin_amdgcn_mfma_f32_16x16x32_bf16(a0, bf, acc[0][c], 0, 0, 0);
            acc[1][c] = __builtin_amdgcn_mfma_f32_16x16x32_bf16(a1, bf, acc[1][c], 0, 0, 0);
        }
    }
    float dv[2][4];
#pragma unroll
    for (int g = 0; g < 2; ++g)
#pragma unroll
        for (int r = 0; r < 4; ++r) {
            int row = row_base + g * 16 + q * 4 + r;
            dv[g][r] = (row < n) ? dinv[row] : 0.f;
        }
#pragma unroll
    for (int g = 0; g < 2; ++g)
#pragma unroll
        for (int c = 0; c < 8; ++c)
#pragma unroll
            for (int r = 0; r < 4; ++r) {
                int row = row_base + g * 16 + q * 4 + r;
                if (row < n) C[(size_t)row * 128 + c * 16 + m] = f32_to_fp8(acc[g][c][r] * dv[g][r]);
            }
}

// ---------------- MFMA GEMM, A bf16 [n,128] x WT4 [32][128] -> bf16 h'4 = h4*dinv ------
__global__ __launch_bounds__(256) void gemm32_bf16A(const bf16* __restrict__ A,
                                                    const bf16* __restrict__ WT,
                                                    const float* __restrict__ dinv,
                                                    bf16* __restrict__ C, int n) {
    int wave = threadIdx.x >> 6;
    int lane = threadIdx.x & 63;
    int m = lane & 15;
    int q = lane >> 4;
    int row_base = blockIdx.x * 64 + wave * 16;
    int arow = min(row_base + m, n - 1);

    f32x4 acc[2];
    acc[0] = (f32x4)(0.f);
    acc[1] = (f32x4)(0.f);

#pragma unroll
    for (int kt = 0; kt < 4; ++kt) {
        short8 af = *(const short8*)&A[(size_t)arow * 128 + kt * 32 + q * 8];
#pragma unroll
        for (int c = 0; c < 2; ++c) {
            short8 bf = *(const short8*)&WT[(size_t)(c * 16 + m) * 128 + kt * 32 + q * 8];
            acc[c] = __builtin_amdgcn_mfma_f32_16x16x32_bf16(af, bf, acc[c], 0, 0, 0);
        }
    }
    float dv[4];
#pragma unroll
    for (int r = 0; r < 4; ++r) {
        int row = row_base + q * 4 + r;
        dv[r] = (row < n) ? dinv[row] : 0.f;
    }
#pragma unroll
    for (int c = 0; c < 2; ++c)
#pragma unroll
        for (int r = 0; r < 4; ++r) {
            int row = row_base + q * 4 + r;
            if (row < n) C[(size_t)row * 32 + c * 16 + m] = __float2bfloat16(acc[c][r] * dv[r]);
        }
}

// ---------------- aggregation F=128 fp8, TWO edges per gather instruction --------------
// Row = 128 B = 32 lanes x uint. Lanes 0-31 fetch edge i, lanes 32-63 edge i+1.
// Pure sum (norm pre-folded); halves combined once per node via shfl_xor(32).
__global__ __launch_bounds__(256) void agg128(const unsigned char* __restrict__ h,
                                              const int* __restrict__ off,
                                              const int* __restrict__ edges,
                                              const float* __restrict__ dinv,
                                              const float* __restrict__ bias,
                                              bf16* __restrict__ out, int n) {
    int wid = (blockIdx.x * blockDim.x + threadIdx.x) >> 6;
    if (wid >= n) return;
    int lane = threadIdx.x & 63;
    int half = lane >> 5;          // which edge of the pair
    int pos = lane & 31;           // uint index within row -> features pos*4..pos*4+3
    const unsigned* h32 = (const unsigned*)h;   // row = 32 uints

    // self-loop: both halves read same row; count it only in half 0
    unsigned su = h32[(size_t)wid * 32 + pos];
    f32x2 slo = __builtin_amdgcn_cvt_pk_f32_fp8((int)su, false);
    f32x2 shi = __builtin_amdgcn_cvt_pk_f32_fp8((int)su, true);
    float a0 = half ? 0.f : slo[0];
    float a1 = half ? 0.f : slo[1];
    float a2 = half ? 0.f : shi[0];
    float a3 = half ? 0.f : shi[1];

    int i0 = off[wid], i1 = off[wid + 1];
    int i = i0;
    for (; i + 16 <= i1; i += 16) {
        unsigned uu[8];
#pragma unroll
        for (int j = 0; j < 8; ++j) {
            int e0 = edges[i + j * 2];
            int e1 = edges[i + j * 2 + 1];
            int s = half ? e1 : e0;
            uu[j] = h32[(size_t)s * 32 + pos];
        }
#pragma unroll
        for (int j = 0; j < 8; ++j) {
            f32x2 lo = __builtin_amdgcn_cvt_pk_f32_fp8((int)uu[j], false);
            f32x2 hi = __builtin_amdgcn_cvt_pk_f32_fp8((int)uu[j], true);
            a0 += lo[0]; a1 += lo[1]; a2 += hi[0]; a3 += hi[1];
        }
    }
    for (; i + 2 <= i1; i += 2) {
        int e0 = edges[i];
        int e1 = edges[i + 1];
        int s = half ? e1 : e0;
        unsigned u = h32[(size_t)s * 32 + pos];
        f32x2 lo = __builtin_amdgcn_cvt_pk_f32_fp8((int)u, false);
        f32x2 hi = __builtin_amdgcn_cvt_pk_f32_fp8((int)u, true);
        a0 += lo[0]; a1 += lo[1]; a2 += hi[0]; a3 += hi[1];
    }
    if (i < i1) {                   // odd leftover: half 0 only
        int e0 = edges[i];
        unsigned u = h32[(size_t)e0 * 32 + pos];
        if (half) u = 0;            // fp8 0x00 == 0.0
        f32x2 lo = __builtin_amdgcn_cvt_pk_f32_fp8((int)u, false);
        f32x2 hi = __builtin_amdgcn_cvt_pk_f32_fp8((int)u, true);
        a0 += lo[0]; a1 += lo[1]; a2 += hi[0]; a3 += hi[1];
    }
    // combine the two halves (lanes l and l^32 accumulate the same features)
    a0 += __shfl_xor(a0, 32);
    a1 += __shfl_xor(a1, 32);
    a2 += __shfl_xor(a2, 32);
    a3 += __shfl_xor(a3, 32);

    float dl = dinv[wid];
    float4 bv = ((const float4*)bias)[pos];
    a0 = fmaxf(a0 * dl + bv.x, 0.f);
    a1 = fmaxf(a1 * dl + bv.y, 0.f);
    a2 = fmaxf(a2 * dl + bv.z, 0.f);
    a3 = fmaxf(a3 * dl + bv.w, 0.f);
    // lane writes dword pos*2+half: features (pos*4 + half*2, +1)
    unsigned pk = half ? pack_bf16x2(a2, a3) : pack_bf16x2(a0, a1);
    ((unsigned*)out)[(size_t)wid * 64 + pos * 2 + half] = pk;
}

// ---------------- aggregation F=32 bf16 gather + log_softmax -> fp32 ----------------
__global__ __launch_bounds__(256) void agg32_lsm(const bf16* __restrict__ h,
                                                 const int* __restrict__ off,
                                                 const int* __restrict__ edges,
                                                 const float* __restrict__ dinv,
                                                 const float* __restrict__ bias,
                                                 float* __restrict__ out, int n) {
    int idx = blockIdx.x * blockDim.x + threadIdx.x;
    int node = idx >> 5;
    if (node >= n) return;
    int lane = idx & 31;
    const unsigned short* hu = (const unsigned short*)h;
    bf16 selfv = h[(size_t)node * 32 + lane];
    float a = __bfloat162float(selfv);                      // self-loop h'4[d]
    int i0 = off[node], i1 = off[node + 1];
    int i = i0;
    for (; i + 8 <= i1; i += 8) {
        int ee[8];
#pragma unroll
        for (int j = 0; j < 8; ++j) ee[j] = edges[i + j];
        unsigned short vv[8];
#pragma unroll
        for (int j = 0; j < 8; ++j) vv[j] = hu[(size_t)ee[j] * 32 + lane];
#pragma unroll
        for (int j = 0; j < 8; ++j) {
            bf16 b = *(bf16*)&vv[j];
            a += __bfloat162float(b);
        }
    }
    for (; i < i1; ++i)
        a += __bfloat162float(h[(size_t)edges[i] * 32 + lane]);
    a = a * dinv[node] + bias[lane];
    float mx = a;
    for (int d = 16; d; d >>= 1) mx = fmaxf(mx, __shfl_xor(mx, d, 32));
    float e = expf(a - mx);
    float ssum = e;
    for (int d = 16; d; d >>= 1) ssum += __shfl_xor(ssum, d, 32);
    out[(size_t)node * 32 + lane] = a - mx - logf(ssum);
}

extern "C" void kernel_launch(void* const* d_in, const int* in_sizes, int n_in,
                              void* d_out, int out_size, void* d_ws, size_t ws_size,
                              hipStream_t stream) {
    const float* x  = (const float*)d_in[0];
    const int*   ei = (const int*)d_in[1];
    const float* W1 = (const float*)d_in[2];
    const float* b1 = (const float*)d_in[3];
    const float* W2 = (const float*)d_in[4];
    const float* b2 = (const float*)d_in[5];
    const float* W3 = (const float*)d_in[6];
    const float* b3 = (const float*)d_in[7];
    const float* W4 = (const float*)d_in[8];
    const float* b4 = (const float*)d_in[9];
    float* out = (float*)d_out;

    const int N = NNODES;
    const int E = in_sizes[1] / 2;
    const int nb = (N + 255) / 256;           // 391 buckets

    char* ws = (char*)d_ws;
    size_t o = 0;
    auto alloc = [&](size_t bytes) -> void* {
        void* p = ws + o;
        o += (bytes + 255) & ~(size_t)255;
        return p;
    };
    int*   bcount  = (int*)alloc((size_t)NBMAX * 4);
    int*   boff    = (int*)alloc((size_t)(NBMAX + 1) * 4);
    int*   bcursor = (int*)alloc((size_t)NBMAX * 4);
    int*   off     = (int*)alloc((size_t)(N + 1) * 4);
    float* dinv    = (float*)alloc((size_t)N * 4);
    int2*  part    = (int2*)alloc((size_t)E * 8);      // aliased as gbuf after build
    int*   edges   = (int*)alloc((size_t)E * 4);
    bf16*  wt1     = (bf16*)alloc((size_t)128 * 128 * 2);
    bf16*  wt2     = (bf16*)alloc((size_t)128 * 128 * 2);
    bf16*  wt3     = (bf16*)alloc((size_t)128 * 128 * 2);
    bf16*  wt4     = (bf16*)alloc((size_t)32 * 128 * 2);
    unsigned char* hbuf = (unsigned char*)alloc((size_t)N * 128);  // fp8 L1-3 / bf16[N*32] L4
    bf16*  gbuf    = (bf16*)part;              // part dead after fine_fill; N*256B == E*8B

    const int* srcv = ei;
    const int* dstv = ei + E;

    hipMemsetAsync(bcount, 0, (size_t)NBMAX * 4, stream);

    int pblocks = (E + CH - 1) / CH;
    bucket_hist<<<pblocks, 256, 0, stream>>>(dstv, bcount, E, nb);
    bucket_scan<<<1, 512, 0, stream>>>(bcount, boff, bcursor, off, nb, N);
    partition<<<pblocks, 256, 0, stream>>>(srcv, dstv, bcursor, part, E, nb);
    bucket_nodes<<<nb, 256, 0, stream>>>(part, boff, dinv, off, N);
    fine_fill<<<nb, 256, 0, stream>>>(part, boff, off, edges, N);

    prep_w<<<64, 256, 0, stream>>>(W1, wt1, 128, 128);
    prep_w<<<64, 256, 0, stream>>>(W2, wt2, 128, 128);
    prep_w<<<64, 256, 0, stream>>>(W3, wt3, 128, 128);
    prep_w<<<16, 256, 0, stream>>>(W4, wt4, 128, 32);

    int gemm128_blocks = (N + 127) / 128;
    int gemm32_blocks = (N + 63) / 64;
    int agg128_blocks = (N + 3) / 4;
    int agg32_blocks = (N * 32 + 255) / 256;

    // Layer 1 (A fp32) -> fp8 h' (pre-scaled by dinv)
    gemm128_f32A<<<gemm128_blocks, 256, 0, stream>>>(x, wt1, dinv, hbuf, N);
    agg128<<<agg128_blocks, 256, 0, stream>>>(hbuf, off, edges, dinv, b1, gbuf, N);
    // Layer 2
    gemm128_bf16A<<<gemm128_blocks, 256, 0, stream>>>(gbuf, wt2, dinv, hbuf, N);
    agg128<<<agg128_blocks, 256, 0, stream>>>(hbuf, off, edges, dinv, b2, gbuf, N);
    // Layer 3
    gemm128_bf16A<<<gemm128_blocks, 256, 0, stream>>>(gbuf, wt3, dinv, hbuf, N);
    agg128<<<agg128_blocks, 256, 0, stream>>>(hbuf, off, edges, dinv, b3, gbuf, N);
    // Layer 4: GEMM to 32 cols (bf16 h'4 - protect final logits), then agg + log_softmax
    gemm32_bf16A<<<gemm32_blocks, 256, 0, stream>>>(gbuf, wt4, dinv, (bf16*)hbuf, N);
    agg32_lsm<<<agg32_blocks, 256, 0, stream>>>((const bf16*)hbuf, off, edges, dinv, b4, out, N);
}

// Round 11
// 517.224 us; speedup vs baseline: 2.5148x; 1.0970x over previous
//
#include <hip/hip_runtime.h>
#include <hip/hip_bf16.h>
#include <math.h>

#define NNODES 100000
#define NBMAX 512          // bucket arrays sized to 512; actual nb = ceil(N/256) = 391
#define CH 8192            // edges per partition block

typedef __hip_bfloat16 bf16;
typedef __attribute__((ext_vector_type(8))) short short8;   // bf16x8 MFMA A/B frag
typedef __attribute__((ext_vector_type(4))) float f32x4;    // MFMA C/D frag
typedef __attribute__((ext_vector_type(2))) float f32x2;

__device__ inline unsigned pack_bf16x2(float a, float b) {
    __hip_bfloat162 p;
    p.x = __float2bfloat16(a);
    p.y = __float2bfloat16(b);
    return *(unsigned*)&p;
}

__device__ inline float2 unpack_bf16x2(unsigned u) {
    __hip_bfloat162 p = *(__hip_bfloat162*)&u;
    return make_float2(__bfloat162float(p.x), __bfloat162float(p.y));
}

__device__ inline unsigned char f32_to_fp8(float v) {
    int p = __builtin_amdgcn_cvt_pk_fp8_f32(v, v, 0, false);   // OCP e4m3 on gfx950
    return (unsigned char)(p & 0xff);
}

// ---------------- phase A: bucket histogram (bucket = dst >> 8) ----------------
__global__ __launch_bounds__(256) void bucket_hist(const int* __restrict__ dst,
                                                   int* __restrict__ bcount, int E, int nb) {
    __shared__ int hist[NBMAX];
    int t = threadIdx.x;
    for (int i = t; i < NBMAX; i += 256) hist[i] = 0;
    __syncthreads();
    int e0 = blockIdx.x * CH;
#pragma unroll
    for (int k = 0; k < 32; ++k) {
        int e = e0 + t + k * 256;
        if (e < E) atomicAdd(&hist[dst[e] >> 8], 1);
    }
    __syncthreads();
    for (int i = t; i < nb; i += 256)
        if (hist[i]) atomicAdd(&bcount[i], hist[i]);
}

// ---------------- phase B: scan bucket counts (1 block, 512 threads) ----------------
__global__ __launch_bounds__(512) void bucket_scan(const int* __restrict__ bcount,
                                                   int* __restrict__ boff,
                                                   int* __restrict__ bcursor,
                                                   int* __restrict__ off, int nb, int n) {
    __shared__ int wsum[8];
    int t = threadIdx.x;
    int v = (t < nb) ? bcount[t] : 0;
    int lane = t & 63, wv = t >> 6;
    int incl = v;
#pragma unroll
    for (int d = 1; d < 64; d <<= 1) {
        int x = __shfl_up(incl, d, 64);
        if (lane >= d) incl += x;
    }
    if (lane == 63) wsum[wv] = incl;
    __syncthreads();
    int wo = 0;
    for (int k = 0; k < wv; ++k) wo += wsum[k];
    int excl = wo + incl - v;
    if (t <= nb) {
        boff[t] = excl;
        if (t < nb) bcursor[t] = excl;
    }
    if (t == nb) off[n] = excl;      // grand total == E
}

// ---------------- phase C: partition edges into bucket-contiguous ranges ----------------
__global__ __launch_bounds__(256) void partition(const int* __restrict__ src,
                                                 const int* __restrict__ dst,
                                                 int* __restrict__ bcursor,
                                                 int2* __restrict__ part, int E, int nb) {
    __shared__ int hist[NBMAX];
    __shared__ int lstart[NBMAX];
    __shared__ int gbase[NBMAX];
    __shared__ int cursor[NBMAX];
    __shared__ int2 sorted[CH];
    int t = threadIdx.x;
    int e0 = blockIdx.x * CH;
    for (int i = t; i < NBMAX; i += 256) hist[i] = 0;
    __syncthreads();
    int mys[32], myd[32];
#pragma unroll
    for (int k = 0; k < 32; ++k) {
        int e = e0 + t + k * 256;
        int s = 0, d = -1;
        if (e < E) { s = src[e]; d = dst[e]; }
        mys[k] = s; myd[k] = d;
        if (d >= 0) atomicAdd(&hist[d >> 8], 1);
    }
    __syncthreads();
    if (t < 64) {
        int base = t * 8;
        int tmp[8];
        int sum = 0;
#pragma unroll
        for (int j = 0; j < 8; ++j) { tmp[j] = hist[base + j]; sum += tmp[j]; }
        int incl = sum;
#pragma unroll
        for (int d = 1; d < 64; d <<= 1) {
            int x = __shfl_up(incl, d, 64);
            if (t >= d) incl += x;
        }
        int excl = incl - sum;
#pragma unroll
        for (int j = 0; j < 8; ++j) {
            lstart[base + j] = excl;
            cursor[base + j] = excl;
            excl += tmp[j];
        }
    }
    __syncthreads();
    for (int i = t; i < nb; i += 256) {
        int c = hist[i];
        gbase[i] = c ? atomicAdd(&bcursor[i], c) : 0;
    }
    __syncthreads();
#pragma unroll
    for (int k = 0; k < 32; ++k) {
        int d = myd[k];
        if (d >= 0) {
            int lpos = atomicAdd(&cursor[d >> 8], 1);
            sorted[lpos] = make_int2(mys[k], d);
        }
    }
    __syncthreads();
    int cnt = min(CH, E - e0);
    for (int i = t; i < cnt; i += 256) {
        int2 rec = sorted[i];
        int b = rec.y >> 8;
        part[gbase[b] + (i - lstart[b])] = rec;
    }
}

// ---------------- phase D: per-bucket node degrees -> off[], dinv[] ----------------
__global__ __launch_bounds__(256) void bucket_nodes(const int2* __restrict__ part,
                                                    const int* __restrict__ boff,
                                                    float* __restrict__ dinv,
                                                    int* __restrict__ off, int n) {
    __shared__ int ndeg[256];
    __shared__ int ws2[4];
    int b = blockIdx.x;
    int t = threadIdx.x;
    ndeg[t] = 0;
    __syncthreads();
    int r0 = boff[b], r1 = boff[b + 1];
    for (int i = r0 + t; i < r1; i += 256)
        atomicAdd(&ndeg[part[i].y & 255], 1);
    __syncthreads();
    int deg = ndeg[t];
    int node = b * 256 + t;
    int lane = t & 63, wv = t >> 6;
    int incl = deg;
#pragma unroll
    for (int d = 1; d < 64; d <<= 1) {
        int x = __shfl_up(incl, d, 64);
        if (lane >= d) incl += x;
    }
    if (lane == 63) ws2[wv] = incl;
    __syncthreads();
    int wo = 0;
    for (int k = 0; k < wv; ++k) wo += ws2[k];
    if (node < n) {
        off[node] = r0 + wo + incl - deg;
        dinv[node] = rsqrtf((float)(deg + 1));     // +1: self-loop
    }
}

// ---------------- phase E: fine CSR fill (int src only; norm folded into h) ----------
__global__ __launch_bounds__(256) void fine_fill(const int2* __restrict__ part,
                                                 const int* __restrict__ boff,
                                                 const int* __restrict__ off,
                                                 int* __restrict__ edges, int n) {
    __shared__ int cur[256];
    __shared__ int offl[256];
    int b = blockIdx.x;
    int t = threadIdx.x;
    int node = b * 256 + t;
    cur[t] = 0;
    offl[t] = (node < n) ? off[node] : 0;
    __syncthreads();
    int r0 = boff[b], r1 = boff[b + 1];
    for (int i = r0 + t; i < r1; i += 256) {
        int2 rec = part[i];
        int dloc = rec.y & 255;
        int lpos = atomicAdd(&cur[dloc], 1);
        edges[offl[dloc] + lpos] = rec.x;
    }
}

// ---------------- weight prep: WT[n][k] = bf16(W[k][n]) ----------------
__global__ void prep_w(const float* __restrict__ W, bf16* __restrict__ WT, int K, int Nout) {
    int idx = blockIdx.x * blockDim.x + threadIdx.x;
    if (idx >= K * Nout) return;
    int nn = idx / K;
    int kk = idx - nn * K;
    WT[idx] = __float2bfloat16(W[kk * Nout + nn]);
}

#define WSTRIDE 136   // bf16 elements; 272 B = 17x16 B (aligned), 2-way LDS conflict only

// ---------------- MFMA GEMM (LDS-staged WT), A fp32 [n,128] -> fp8 h' = h*dinv[row] ----
__global__ __launch_bounds__(256) void gemm128_f32A(const float* __restrict__ A,
                                                    const bf16* __restrict__ WT,
                                                    const float* __restrict__ dinv,
                                                    unsigned char* __restrict__ C, int n) {
    __shared__ bf16 wl[128 * WSTRIDE];   // 34 KB
    int t = threadIdx.x;
#pragma unroll
    for (int l = 0; l < 8; ++l) {
        int chunk = t + l * 256;           // 0..2047, 16B chunks
        int row = chunk >> 4, ch = chunk & 15;
        *(uint4*)&wl[row * WSTRIDE + ch * 8] = *(const uint4*)&WT[row * 128 + ch * 8];
    }
    __syncthreads();
    int wave = t >> 6, lane = t & 63;
    int m = lane & 15, q = lane >> 4;
    int row_base = blockIdx.x * 128 + wave * 32;
    int r0 = min(row_base + m, n - 1);
    int r1 = min(row_base + 16 + m, n - 1);

    f32x4 acc[2][8];
#pragma unroll
    for (int g = 0; g < 2; ++g)
#pragma unroll
        for (int c = 0; c < 8; ++c) acc[g][c] = (f32x4)(0.f);

#pragma unroll
    for (int kt = 0; kt < 4; ++kt) {
        short8 af[2];
#pragma unroll
        for (int g = 0; g < 2; ++g) {
            const float* ap = &A[(size_t)(g ? r1 : r0) * 128 + kt * 32 + q * 8];
            float4 f0 = *(const float4*)ap;
            float4 f1 = *(const float4*)(ap + 4);
            union { uint4 u; short8 s; } cv;
            cv.u.x = pack_bf16x2(f0.x, f0.y);
            cv.u.y = pack_bf16x2(f0.z, f0.w);
            cv.u.z = pack_bf16x2(f1.x, f1.y);
            cv.u.w = pack_bf16x2(f1.z, f1.w);
            af[g] = cv.s;
        }
#pragma unroll
        for (int c = 0; c < 8; ++c) {
            short8 bf = *(const short8*)&wl[(c * 16 + m) * WSTRIDE + kt * 32 + q * 8];
            acc[0][c] = __builtin_amdgcn_mfma_f32_16x16x32_bf16(af[0], bf, acc[0][c], 0, 0, 0);
            acc[1][c] = __builtin_amdgcn_mfma_f32_16x16x32_bf16(af[1], bf, acc[1][c], 0, 0, 0);
        }
    }
    float dv[2][4];
#pragma unroll
    for (int g = 0; g < 2; ++g)
#pragma unroll
        for (int r = 0; r < 4; ++r) {
            int row = row_base + g * 16 + q * 4 + r;
            dv[g][r] = (row < n) ? dinv[row] : 0.f;
        }
#pragma unroll
    for (int g = 0; g < 2; ++g)
#pragma unroll
        for (int c = 0; c < 8; ++c)
#pragma unroll
            for (int r = 0; r < 4; ++r) {
                int row = row_base + g * 16 + q * 4 + r;
                if (row < n) C[(size_t)row * 128 + c * 16 + m] = f32_to_fp8(acc[g][c][r] * dv[g][r]);
            }
}

// ---------------- MFMA GEMM (LDS-staged WT), A bf16 [n,128] -> fp8 h' ----------------
__global__ __launch_bounds__(256) void gemm128_bf16A(const bf16* __restrict__ A,
                                                     const bf16* __restrict__ WT,
                                                     const float* __restrict__ dinv,
                                                     unsigned char* __restrict__ C, int n) {
    __shared__ bf16 wl[128 * WSTRIDE];   // 34 KB
    int t = threadIdx.x;
#pragma unroll
    for (int l = 0; l < 8; ++l) {
        int chunk = t + l * 256;
        int row = chunk >> 4, ch = chunk & 15;
        *(uint4*)&wl[row * WSTRIDE + ch * 8] = *(const uint4*)&WT[row * 128 + ch * 8];
    }
    __syncthreads();
    int wave = t >> 6, lane = t & 63;
    int m = lane & 15, q = lane >> 4;
    int row_base = blockIdx.x * 128 + wave * 32;
    int r0 = min(row_base + m, n - 1);
    int r1 = min(row_base + 16 + m, n - 1);

    f32x4 acc[2][8];
#pragma unroll
    for (int g = 0; g < 2; ++g)
#pragma unroll
        for (int c = 0; c < 8; ++c) acc[g][c] = (f32x4)(0.f);

#pragma unroll
    for (int kt = 0; kt < 4; ++kt) {
        short8 a0 = *(const short8*)&A[(size_t)r0 * 128 + kt * 32 + q * 8];
        short8 a1 = *(const short8*)&A[(size_t)r1 * 128 + kt * 32 + q * 8];
#pragma unroll
        for (int c = 0; c < 8; ++c) {
            short8 bf = *(const short8*)&wl[(c * 16 + m) * WSTRIDE + kt * 32 + q * 8];
            acc[0][c] = __builtin_amdgcn_mfma_f32_16x16x32_bf16(a0, bf, acc[0][c], 0, 0, 0);
            acc[1][c] = __builtin_amdgcn_mfma_f32_16x16x32_bf16(a1, bf, acc[1][c], 0, 0, 0);
        }
    }
    float dv[2][4];
#pragma unroll
    for (int g = 0; g < 2; ++g)
#pragma unroll
        for (int r = 0; r < 4; ++r) {
            int row = row_base + g * 16 + q * 4 + r;
            dv[g][r] = (row < n) ? dinv[row] : 0.f;
        }
#pragma unroll
    for (int g = 0; g < 2; ++g)
#pragma unroll
        for (int c = 0; c < 8; ++c)
#pragma unroll
            for (int r = 0; r < 4; ++r) {
                int row = row_base + g * 16 + q * 4 + r;
                if (row < n) C[(size_t)row * 128 + c * 16 + m] = f32_to_fp8(acc[g][c][r] * dv[g][r]);
            }
}

// ---------------- MFMA GEMM, A bf16 [n,128] x WT4 [32][128] -> bf16 h'4 = h4*dinv ------
__global__ __launch_bounds__(256) void gemm32_bf16A(const bf16* __restrict__ A,
                                                    const bf16* __restrict__ WT,
                                                    const float* __restrict__ dinv,
                                                    bf16* __restrict__ C, int n) {
    int wave = threadIdx.x >> 6;
    int lane = threadIdx.x & 63;
    int m = lane & 15;
    int q = lane >> 4;
    int row_base = blockIdx.x * 64 + wave * 16;
    int arow = min(row_base + m, n - 1);

    f32x4 acc[2];
    acc[0] = (f32x4)(0.f);
    acc[1] = (f32x4)(0.f);

#pragma unroll
    for (int kt = 0; kt < 4; ++kt) {
        short8 af = *(const short8*)&A[(size_t)arow * 128 + kt * 32 + q * 8];
#pragma unroll
        for (int c = 0; c < 2; ++c) {
            short8 bf = *(const short8*)&WT[(size_t)(c * 16 + m) * 128 + kt * 32 + q * 8];
            acc[c] = __builtin_amdgcn_mfma_f32_16x16x32_bf16(af, bf, acc[c], 0, 0, 0);
        }
    }
    float dv[4];
#pragma unroll
    for (int r = 0; r < 4; ++r) {
        int row = row_base + q * 4 + r;
        dv[r] = (row < n) ? dinv[row] : 0.f;
    }
#pragma unroll
    for (int c = 0; c < 2; ++c)
#pragma unroll
        for (int r = 0; r < 4; ++r) {
            int row = row_base + q * 4 + r;
            if (row < n) C[(size_t)row * 32 + c * 16 + m] = __float2bfloat16(acc[c][r] * dv[r]);
        }
}

// ---------------- aggregation F=128 fp8, two edges/gather, packed f32x2 accum ----------
// Row = 128 B = 32 lanes x uint. Lanes 0-31 fetch edge i, lanes 32-63 edge i+1.
// Pure sum (norm pre-folded); halves combined once per node via shfl_xor(32).
__global__ __launch_bounds__(256) void agg128(const unsigned char* __restrict__ h,
                                              const int* __restrict__ off,
                                              const int* __restrict__ edges,
                                              const float* __restrict__ dinv,
                                              const float* __restrict__ bias,
                                              bf16* __restrict__ out, int n) {
    int wid = (blockIdx.x * blockDim.x + threadIdx.x) >> 6;
    if (wid >= n) return;
    int lane = threadIdx.x & 63;
    int half = lane >> 5;          // which edge of the pair
    int pos = lane & 31;           // uint index within row -> features pos*4..pos*4+3
    const unsigned* h32 = (const unsigned*)h;   // row = 32 uints

    // self-loop: both halves read same row; count it only in half 0
    unsigned su = half ? 0u : h32[(size_t)wid * 32 + pos];
    f32x2 accL = __builtin_amdgcn_cvt_pk_f32_fp8((int)su, false);
    f32x2 accH = __builtin_amdgcn_cvt_pk_f32_fp8((int)su, true);

    int i0 = off[wid], i1 = off[wid + 1];
    int i = i0;
    for (; i + 32 <= i1; i += 32) {           // 16 gathers in flight
        unsigned uu[16];
#pragma unroll
        for (int j = 0; j < 16; ++j) {
            int s = edges[i + j * 2 + half];
            uu[j] = h32[(size_t)s * 32 + pos];
        }
#pragma unroll
        for (int j = 0; j < 16; ++j) {
            accL += __builtin_amdgcn_cvt_pk_f32_fp8((int)uu[j], false);
            accH += __builtin_amdgcn_cvt_pk_f32_fp8((int)uu[j], true);
        }
    }
    for (; i + 8 <= i1; i += 8) {             // 4 gathers in flight
        unsigned uu[4];
#pragma unroll
        for (int j = 0; j < 4; ++j) {
            int s = edges[i + j * 2 + half];
            uu[j] = h32[(size_t)s * 32 + pos];
        }
#pragma unroll
        for (int j = 0; j < 4; ++j) {
            accL += __builtin_amdgcn_cvt_pk_f32_fp8((int)uu[j], false);
            accH += __builtin_amdgcn_cvt_pk_f32_fp8((int)uu[j], true);
        }
    }
    for (; i + 2 <= i1; i += 2) {
        int s = edges[i + half];
        unsigned u = h32[(size_t)s * 32 + pos];
        accL += __builtin_amdgcn_cvt_pk_f32_fp8((int)u, false);
        accH += __builtin_amdgcn_cvt_pk_f32_fp8((int)u, true);
    }
    if (i < i1) {                   // odd leftover: half 0 only
        unsigned u = half ? 0u : h32[(size_t)edges[i] * 32 + pos];
        accL += __builtin_amdgcn_cvt_pk_f32_fp8((int)u, false);
        accH += __builtin_amdgcn_cvt_pk_f32_fp8((int)u, true);
    }
    // combine the two halves (lanes l and l^32 accumulate the same features)
    float a0 = accL[0] + __shfl_xor(accL[0], 32);
    float a1 = accL[1] + __shfl_xor(accL[1], 32);
    float a2 = accH[0] + __shfl_xor(accH[0], 32);
    float a3 = accH[1] + __shfl_xor(accH[1], 32);

    float dl = dinv[wid];
    float4 bv = ((const float4*)bias)[pos];
    a0 = fmaxf(a0 * dl + bv.x, 0.f);
    a1 = fmaxf(a1 * dl + bv.y, 0.f);
    a2 = fmaxf(a2 * dl + bv.z, 0.f);
    a3 = fmaxf(a3 * dl + bv.w, 0.f);
    // lane writes dword pos*2+half: features (pos*4 + half*2, +1)
    unsigned pk = half ? pack_bf16x2(a2, a3) : pack_bf16x2(a0, a1);
    ((unsigned*)out)[(size_t)wid * 64 + pos * 2 + half] = pk;
}

// ---------------- aggregation F=32 bf16, two edges/gather + log_softmax -> fp32 --------
// Row = 64 B = 16 uints. sub = feature pair, pr = edge parity; combine via shfl_xor(16).
__global__ __launch_bounds__(256) void agg32_lsm(const bf16* __restrict__ h,
                                                 const int* __restrict__ off,
                                                 const int* __restrict__ edges,
                                                 const float* __restrict__ dinv,
                                                 const float* __restrict__ bias,
                                                 float* __restrict__ out, int n) {
    int idx = blockIdx.x * blockDim.x + threadIdx.x;
    int node = idx >> 5;
    if (node >= n) return;
    int lane5 = idx & 31;
    int sub = lane5 & 15;      // feature pair: features sub*2, sub*2+1
    int pr = lane5 >> 4;       // edge parity
    const unsigned* h4 = (const unsigned*)h;    // row = 16 uints

    unsigned su = pr ? 0u : h4[(size_t)node * 16 + sub];   // self-loop once
    float2 sf = unpack_bf16x2(su);
    f32x2 acc = {sf.x, sf.y};

    int i0 = off[node], i1 = off[node + 1];
    int i = i0;
    for (; i + 16 <= i1; i += 16) {
        unsigned uu[8];
#pragma unroll
        for (int j = 0; j < 8; ++j) {
            int s = edges[i + j * 2 + pr];
            uu[j] = h4[(size_t)s * 16 + sub];
        }
#pragma unroll
        for (int j = 0; j < 8; ++j) {
            float2 f = unpack_bf16x2(uu[j]);
            acc[0] += f.x; acc[1] += f.y;
        }
    }
    for (; i + 2 <= i1; i += 2) {
        int s = edges[i + pr];
        float2 f = unpack_bf16x2(h4[(size_t)s * 16 + sub]);
        acc[0] += f.x; acc[1] += f.y;
    }
    if (i < i1) {
        unsigned u = pr ? 0u : h4[(size_t)edges[i] * 16 + sub];
        float2 f = unpack_bf16x2(u);
        acc[0] += f.x; acc[1] += f.y;
    }
    // combine parities: lanes l and l^16 hold the same features
    float s0 = acc[0] + __shfl_xor(acc[0], 16);
    float s1 = acc[1] + __shfl_xor(acc[1], 16);

    float dl = dinv[node];
    float2 bv = *(const float2*)&bias[sub * 2];
    float a0 = s0 * dl + bv.x;
    float a1 = s1 * dl + bv.y;
    // log_softmax over 32 features held as pairs in each 16-lane group (duplicated)
    float m = fmaxf(a0, a1);
    for (int d = 8; d; d >>= 1) m = fmaxf(m, __shfl_xor(m, d));
    float e = expf(a0 - m) + expf(a1 - m);
    for (int d = 8; d; d >>= 1) e += __shfl_xor(e, d);
    float lse = m + logf(e);
    if (pr == 0)
        *(float2*)&out[(size_t)node * 32 + sub * 2] = make_float2(a0 - lse, a1 - lse);
}

extern "C" void kernel_launch(void* const* d_in, const int* in_sizes, int n_in,
                              void* d_out, int out_size, void* d_ws, size_t ws_size,
                              hipStream_t stream) {
    const float* x  = (const float*)d_in[0];
    const int*   ei = (const int*)d_in[1];
    const float* W1 = (const float*)d_in[2];
    const float* b1 = (const float*)d_in[3];
    const float* W2 = (const float*)d_in[4];
    const float* b2 = (const float*)d_in[5];
    const float* W3 = (const float*)d_in[6];
    const float* b3 = (const float*)d_in[7];
    const float* W4 = (const float*)d_in[8];
    const float* b4 = (const float*)d_in[9];
    float* out = (float*)d_out;

    const int N = NNODES;
    const int E = in_sizes[1] / 2;
    const int nb = (N + 255) / 256;           // 391 buckets

    char* ws = (char*)d_ws;
    size_t o = 0;
    auto alloc = [&](size_t bytes) -> void* {
        void* p = ws + o;
        o += (bytes + 255) & ~(size_t)255;
        return p;
    };
    int*   bcount  = (int*)alloc((size_t)NBMAX * 4);
    int*   boff    = (int*)alloc((size_t)(NBMAX + 1) * 4);
    int*   bcursor = (int*)alloc((size_t)NBMAX * 4);
    int*   off     = (int*)alloc((size_t)(N + 1) * 4);
    float* dinv    = (float*)alloc((size_t)N * 4);
    int2*  part    = (int2*)alloc((size_t)E * 8);      // aliased as gbuf after build
    int*   edges   = (int*)alloc((size_t)E * 4);
    bf16*  wt1     = (bf16*)alloc((size_t)128 * 128 * 2);
    bf16*  wt2     = (bf16*)alloc((size_t)128 * 128 * 2);
    bf16*  wt3     = (bf16*)alloc((size_t)128 * 128 * 2);
    bf16*  wt4     = (bf16*)alloc((size_t)32 * 128 * 2);
    unsigned char* hbuf = (unsigned char*)alloc((size_t)N * 128);  // fp8 L1-3 / bf16[N*32] L4
    bf16*  gbuf    = (bf16*)part;              // part dead after fine_fill; N*256B == E*8B

    const int* srcv = ei;
    const int* dstv = ei + E;

    hipMemsetAsync(bcount, 0, (size_t)NBMAX * 4, stream);

    int pblocks = (E + CH - 1) / CH;
    bucket_hist<<<pblocks, 256, 0, stream>>>(dstv, bcount, E, nb);
    bucket_scan<<<1, 512, 0, stream>>>(bcount, boff, bcursor, off, nb, N);
    partition<<<pblocks, 256, 0, stream>>>(srcv, dstv, bcursor, part, E, nb);
    bucket_nodes<<<nb, 256, 0, stream>>>(part, boff, dinv, off, N);
    fine_fill<<<nb, 256, 0, stream>>>(part, boff, off, edges, N);

    prep_w<<<64, 256, 0, stream>>>(W1, wt1, 128, 128);
    prep_w<<<64, 256, 0, stream>>>(W2, wt2, 128, 128);
    prep_w<<<64, 256, 0, stream>>>(W3, wt3, 128, 128);
    prep_w<<<16, 256, 0, stream>>>(W4, wt4, 128, 32);

    int gemm128_blocks = (N + 127) / 128;
    int gemm32_blocks = (N + 63) / 64;
    int agg128_blocks = (N + 3) / 4;
    int agg32_blocks = (N * 32 + 255) / 256;

    // Layer 1 (A fp32) -> fp8 h' (pre-scaled by dinv)
    gemm128_f32A<<<gemm128_blocks, 256, 0, stream>>>(x, wt1, dinv, hbuf, N);
    agg128<<<agg128_blocks, 256, 0, stream>>>(hbuf, off, edges, dinv, b1, gbuf, N);
    // Layer 2
    gemm128_bf16A<<<gemm128_blocks, 256, 0, stream>>>(gbuf, wt2, dinv, hbuf, N);
    agg128<<<agg128_blocks, 256, 0, stream>>>(hbuf, off, edges, dinv, b2, gbuf, N);
    // Layer 3
    gemm128_bf16A<<<gemm128_blocks, 256, 0, stream>>>(gbuf, wt3, dinv, hbuf, N);
    agg128<<<agg128_blocks, 256, 0, stream>>>(hbuf, off, edges, dinv, b3, gbuf, N);
    // Layer 4: GEMM to 32 cols (bf16 h'4 - protect final logits), then agg + log_softmax
    gemm32_bf16A<<<gemm32_blocks, 256, 0, stream>>>(gbuf, wt4, dinv, (bf16*)hbuf, N);
    agg32_lsm<<<agg32_blocks, 256, 0, stream>>>((const bf16*)hbuf, off, edges, dinv, b4, out, N);
}